// Round 3
// baseline (863.122 us; speedup 1.0000x reference)
//
#include <hip/hip_runtime.h>
#include <cstdint>
#include <cstddef>

#define TSEQ 4096
#define BATCH 2
#define DIM 256
#define NHEAD 8
#define HDIM 32
#define NLAYER 4
#define FFDIM 1024
#define SPLITN 2048
#define MROWS (BATCH * TSEQ)   // 8192

// (1/sqrt(HD)) * log2(e)  -- folded into q at the QKV epilogue so softmax uses exp2 directly
#define QSCALE 0.2550784545f

typedef __attribute__((ext_vector_type(4))) float f32x4;
typedef __attribute__((ext_vector_type(8))) short bf16x8;

__device__ __forceinline__ short f2bf(float f) {
  union { float f; uint32_t u; } v; v.f = f;
  uint32_t r = v.u + 0x7fffu + ((v.u >> 16) & 1u);
  return (short)(r >> 16);
}

// raw v_exp_f32 -- inputs here are bounded, no libm range fixup needed
__device__ __forceinline__ float fast_exp2(float x) {
#if __has_builtin(__builtin_amdgcn_exp2f)
  return __builtin_amdgcn_exp2f(x);
#else
  float r;
  asm volatile("v_exp_f32 %0, %1\n\ts_nop 1" : "=v"(r) : "v"(x));
  return r;
#endif
}

// pack two fp32 -> two bf16 (round-half-up; 3 VALU ops)
__device__ __forceinline__ uint32_t pack2bf(float a, float b) {
  union { float f; uint32_t u; } ua, ub; ua.f = a; ub.f = b;
  return ((ua.u + 0x8000u) >> 16) | ((ub.u + 0x8000u) & 0xffff0000u);
}

__device__ __forceinline__ float gelu_f(float x) {
  // JAX gelu approximate=True: 0.5x(1+tanh(sqrt(2/pi)(x+0.044715x^3)))
  float u = 0.7978845608f * x * (1.0f + 0.044715f * x * x);
  u = fminf(fmaxf(u, -20.f), 20.f);
  float e = fast_exp2(2.885390082f * u);   // exp(2u)
  float t = (e - 1.0f) / (e + 1.0f);
  return 0.5f * x * (1.0f + t);
}

#define AS1 __attribute__((address_space(1)))
#define AS3 __attribute__((address_space(3)))
__device__ __forceinline__ void gload16(const void* g, void* l) {
  __builtin_amdgcn_global_load_lds((AS1 void*)g, (AS3 void*)l, 16, 0, 0);
}

// ---------------------------------------------------------------- weight prep
__global__ __launch_bounds__(256) void prep_w(
    const float* __restrict__ Wq, const float* __restrict__ Wk,
    const float* __restrict__ Wv, const float* __restrict__ Wo,
    const float* __restrict__ W1, const float* __restrict__ W2,
    short* __restrict__ qkvT, short* __restrict__ woT,
    short* __restrict__ w1T, short* __restrict__ w2T)
{
  const int NQKV = NLAYER * 768 * DIM;   // 786432
  const int NO   = NLAYER * DIM * DIM;   // 262144
  const int NF   = NLAYER * FFDIM * DIM; // 1048576
  const int total = NQKV + NO + 2 * NF;
  for (int idx = blockIdx.x * 256 + threadIdx.x; idx < total; idx += gridDim.x * 256) {
    if (idx < NQKV) {                       // qkvT[l][n:768][k:256]
      const int l = idx / (768 * DIM);
      const int rem = idx - l * 768 * DIM;
      const int n = rem >> 8, k = rem & 255;
      const float* src = (n < 256) ? Wq : ((n < 512) ? Wk : Wv);
      qkvT[idx] = f2bf(src[((size_t)l * DIM + k) * DIM + (n & 255)]);
    } else if (idx < NQKV + NO) {           // woT[l][n:256][k:256]
      const int j = idx - NQKV;
      const int l = j >> 16;
      const int rem = j & 65535;
      const int n = rem >> 8, k = rem & 255;
      woT[j] = f2bf(Wo[((size_t)l * DIM + k) * DIM + n]);
    } else if (idx < NQKV + NO + NF) {      // w1T[l][n:1024][k:256]
      const int j = idx - NQKV - NO;
      const int l = j >> 18;
      const int rem = j & 262143;
      const int n = rem >> 8, k = rem & 255;
      w1T[j] = f2bf(W1[((size_t)l * DIM + k) * FFDIM + n]);
    } else {                                // w2T[l][n:256][k:1024]
      const int j = idx - NQKV - NO - NF;
      const int l = j >> 18;
      const int rem = j & 262143;
      const int n = rem >> 10, k = rem & 1023;
      w2T[j] = f2bf(W2[((size_t)l * FFDIM + k) * DIM + n]);
    }
  }
}

// ------------------------------------------------------------------- x prep
__global__ __launch_bounds__(256) void prep_x(
    const float* __restrict__ rows, const float* __restrict__ tte,
    float* __restrict__ xf, short* __restrict__ xb)
{
  const size_t idx = (size_t)blockIdx.x * 256 + threadIdx.x;  // float4 index
  float4 v = ((const float4*)rows)[idx];
  const size_t e = idx * 4;
  const int m = (int)(e >> 8);
  const int d = (int)(e & 255);
  const int t = m & (TSEQ - 1);
  const int bb = m >> 12;
  if (t < SPLITN) {
    const float4 a = ((const float4*)tte)[((size_t)bb * SPLITN + t) * (DIM / 4) + (d >> 2)];
    v.x += a.x; v.y += a.y; v.z += a.z; v.w += a.w;
  }
  ((float4*)xf)[idx] = v;
  short4 pk; pk.x = f2bf(v.x); pk.y = f2bf(v.y); pk.z = f2bf(v.z); pk.w = f2bf(v.w);
  ((short4*)xb)[idx] = pk;
}

// ---------------------------------------------------------------------- GEMM
#define GBM 128
#define GBN 64
#define GBK 64

template<int EPI>
__global__ __launch_bounds__(256, 4) void gemm_bt(
    const short* __restrict__ A, const short* __restrict__ BT,
    const float* __restrict__ bias0, const float* __restrict__ bias1,
    const float* __restrict__ bias2, void* __restrict__ Cout,
    int M, int N, int K)
{
  __shared__ short As[GBM * GBK];
  __shared__ short Bs[GBN * GBK];
  const int tid = threadIdx.x;
  const int lane = tid & 63;
  const int wave = tid >> 6;
  const int wm = wave & 1, wn = wave >> 1;
  const int col = lane & 15, quad = lane >> 4;

  const short* Ab = A + (size_t)blockIdx.x * GBM * K;
  const short* Bb = BT + (size_t)blockIdx.y * GBN * K;

  const f32x4 fz = {0.f, 0.f, 0.f, 0.f};
  f32x4 acc[4][2];
#pragma unroll
  for (int i = 0; i < 4; ++i)
#pragma unroll
    for (int j = 0; j < 2; ++j) acc[i][j] = fz;

  for (int k0 = 0; k0 < K; k0 += GBK) {
#pragma unroll
    for (int p = 0; p < 4; ++p) {
      int i = p * 256 + tid;
      gload16(Ab + (size_t)(i >> 3) * K + k0 + (i & 7) * 8, &As[i * 8]);
    }
#pragma unroll
    for (int p = 0; p < 2; ++p) {
      int i = p * 256 + tid;
      gload16(Bb + (size_t)(i >> 3) * K + k0 + (i & 7) * 8, &Bs[i * 8]);
    }
    __syncthreads();
#pragma unroll
    for (int ks = 0; ks < GBK; ks += 32) {
      bf16x8 af[4], bfr[2];
#pragma unroll
      for (int tm = 0; tm < 4; ++tm)
        af[tm] = *(const bf16x8*)&As[(wm * 64 + tm * 16 + col) * GBK + ks + quad * 8];
#pragma unroll
      for (int tn = 0; tn < 2; ++tn)
        bfr[tn] = *(const bf16x8*)&Bs[(wn * 32 + tn * 16 + col) * GBK + ks + quad * 8];
#pragma unroll
      for (int tm = 0; tm < 4; ++tm)
#pragma unroll
        for (int tn = 0; tn < 2; ++tn)
          acc[tm][tn] = __builtin_amdgcn_mfma_f32_16x16x32_bf16(af[tm], bfr[tn], acc[tm][tn], 0, 0, 0);
    }
    __syncthreads();
  }

#pragma unroll
  for (int tm = 0; tm < 4; ++tm) {
    const int mbase = blockIdx.x * GBM + wm * 64 + tm * 16 + quad * 4;
#pragma unroll
    for (int tn = 0; tn < 2; ++tn) {
      const int n = blockIdx.y * GBN + wn * 32 + tn * 16 + col;
      float bv;
      if (EPI == 1) bv = (n < 256) ? bias0[n] : ((n < 512) ? bias1[n - 256] : bias2[n - 512]);
      else          bv = bias0[n];
#pragma unroll
      for (int r = 0; r < 4; ++r) {
        float v = acc[tm][tn][r] + bv;
        size_t off = (size_t)(mbase + r) * N + n;
        if (EPI == 1) {
          if (n < 256) v *= QSCALE;
          ((short*)Cout)[off] = f2bf(v);
        } else if (EPI == 2) {
          ((float*)Cout)[off] = v;
        } else {
          ((short*)Cout)[off] = f2bf(gelu_f(v));
        }
      }
    }
  }
}

// ------------------------------------------------------------- V transpose
__global__ __launch_bounds__(256) void transpose_v(
    const short* __restrict__ qkv, short* __restrict__ vt)
{
  __shared__ short tile[32][33];
  const int t0 = blockIdx.x * 32;
  const int c0 = blockIdx.y * 32;
  const int b = blockIdx.z;
  const int tx = threadIdx.x & 31, ty = threadIdx.x >> 5;
#pragma unroll
  for (int i = 0; i < 4; ++i) {
    const int t = t0 + ty + i * 8;
    tile[ty + i * 8][tx] = qkv[(size_t)(b * TSEQ + t) * 768 + 512 + c0 + tx];
  }
  __syncthreads();
#pragma unroll
  for (int i = 0; i < 4; ++i) {
    const int c = c0 + ty + i * 8;
    vt[(size_t)(b * DIM + c) * TSEQ + t0 + tx] = tile[tx][ty + i * 8];
  }
}

// ----------------------------------------------------------------- attention
// One wave = 16 queries of one (b,h).  Depth-2 register prefetch on K/V.
// lsum computed by MFMA against a ones B-fragment (reuses pf); its C-layout
// row index == o's row index, so no cross-lane shuffles are needed.
__global__ __launch_bounds__(256) void attn_kernel(
    const short* __restrict__ qkv, const short* __restrict__ vt,
    short* __restrict__ outp)
{
  __shared__ short Pall[4][16][40];   // per-wave, padded rows (80 B = 5x16 B)
  const int tid = threadIdx.x;
  const int lane = tid & 63;
  const int wave = tid >> 6;
  const int col = lane & 15, quad = lane >> 4;
  const int bh = blockIdx.y;
  const int b = bh >> 3, h = bh & 7;
  const int q0 = blockIdx.x * 64 + wave * 16;

  short (*P)[40] = Pall[wave];

  const short* qbase = qkv + (size_t)b * TSEQ * 768 + h * HDIM;
  const short* kbase = qbase + 256;
  const short* vtb = vt + (size_t)bh * HDIM * TSEQ;

  const bf16x8 qf = *(const bf16x8*)(qbase + (size_t)(q0 + col) * 768 + quad * 8);

  // per-lane running pointers (strength-reduced addressing)
  const short* pk0 = kbase + (size_t)col * 768 + quad * 8;
  const short* pk1 = pk0 + (size_t)16 * 768;
  const short* pv0 = vtb + (size_t)col * TSEQ + quad * 8;
  const short* pv1 = pv0 + (size_t)16 * TSEQ;

  bf16x8 ones;
#pragma unroll
  for (int i = 0; i < 8; ++i) ones[i] = (short)0x3F80;  // bf16 1.0

  const f32x4 fz = {0.f, 0.f, 0.f, 0.f};
  f32x4 o0 = fz, o1 = fz, lacc = fz;

  // depth-2 prefetch pipeline: A = chunk k0, B = chunk k0+32
  bf16x8 kA0 = *(const bf16x8*)(pk0);
  bf16x8 kA1 = *(const bf16x8*)(pk1);
  bf16x8 vA0 = *(const bf16x8*)(pv0);
  bf16x8 vA1 = *(const bf16x8*)(pv1);
  bf16x8 kB0 = *(const bf16x8*)(pk0 + (size_t)32 * 768);
  bf16x8 kB1 = *(const bf16x8*)(pk1 + (size_t)32 * 768);
  bf16x8 vB0 = *(const bf16x8*)(pv0 + 32);
  bf16x8 vB1 = *(const bf16x8*)(pv1 + 32);

#pragma unroll 2
  for (int k0 = 0; k0 < SPLITN; k0 += 32) {
    const int kn = (k0 + 64) & (SPLITN - 1);   // wraps to a valid region at tail
    bf16x8 kC0 = *(const bf16x8*)(pk0 + (size_t)kn * 768);
    bf16x8 kC1 = *(const bf16x8*)(pk1 + (size_t)kn * 768);
    bf16x8 vC0 = *(const bf16x8*)(pv0 + kn);
    bf16x8 vC1 = *(const bf16x8*)(pv1 + kn);

    f32x4 s0 = __builtin_amdgcn_mfma_f32_16x16x32_bf16(kA0, qf, fz, 0, 0, 0);
    f32x4 s1 = __builtin_amdgcn_mfma_f32_16x16x32_bf16(kA1, qf, fz, 0, 0, 0);
    uint2 w0, w1;
    w0.x = pack2bf(fast_exp2(s0[0]), fast_exp2(s0[1]));
    w0.y = pack2bf(fast_exp2(s0[2]), fast_exp2(s0[3]));
    w1.x = pack2bf(fast_exp2(s1[0]), fast_exp2(s1[1]));
    w1.y = pack2bf(fast_exp2(s1[2]), fast_exp2(s1[3]));
    asm volatile("" ::: "memory");
    *(uint2*)&P[col][quad * 4] = w0;
    *(uint2*)&P[col][16 + quad * 4] = w1;
    asm volatile("s_waitcnt lgkmcnt(0)" ::: "memory");  // LDS-only fence
    bf16x8 pf = *(const bf16x8*)&P[col][quad * 8];
    o0 = __builtin_amdgcn_mfma_f32_16x16x32_bf16(pf, vA0, o0, 0, 0, 0);
    o1 = __builtin_amdgcn_mfma_f32_16x16x32_bf16(pf, vA1, o1, 0, 0, 0);
    lacc = __builtin_amdgcn_mfma_f32_16x16x32_bf16(pf, ones, lacc, 0, 0, 0);

    kA0 = kB0; kA1 = kB1; vA0 = vB0; vA1 = vB1;
    kB0 = kC0; kB1 = kC1; vB0 = vC0; vB1 = vC1;
  }

  if (q0 >= SPLITN) {  // wave-uniform: self-key chunk for test queries
    bf16x8 kf = *(const bf16x8*)(kbase + (size_t)(q0 + col) * 768 + quad * 8);
    // keys >=16 of this chunk have P==0; duplicated V reads stay in bounds
    bf16x8 vf0 = *(const bf16x8*)(vtb + (size_t)col * TSEQ + q0 + (quad & 1) * 8);
    bf16x8 vf1 = *(const bf16x8*)(vtb + (size_t)(16 + col) * TSEQ + q0 + (quad & 1) * 8);
    f32x4 sd = __builtin_amdgcn_mfma_f32_16x16x32_bf16(kf, qf, fz, 0, 0, 0);
    float pd[4];
#pragma unroll
    for (int r = 0; r < 4; ++r) {
      const bool valid = (quad * 4 + r) == col;  // key index == query index
      pd[r] = valid ? fast_exp2(sd[r]) : 0.f;
    }
    uint2 w0, wz;
    w0.x = pack2bf(pd[0], pd[1]); w0.y = pack2bf(pd[2], pd[3]);
    wz.x = 0; wz.y = 0;
    asm volatile("" ::: "memory");
    *(uint2*)&P[col][quad * 4] = w0;
    *(uint2*)&P[col][16 + quad * 4] = wz;
    asm volatile("s_waitcnt lgkmcnt(0)" ::: "memory");
    bf16x8 pf = *(const bf16x8*)&P[col][quad * 8];
    o0 = __builtin_amdgcn_mfma_f32_16x16x32_bf16(pf, vf0, o0, 0, 0, 0);
    o1 = __builtin_amdgcn_mfma_f32_16x16x32_bf16(pf, vf1, o1, 0, 0, 0);
    lacc = __builtin_amdgcn_mfma_f32_16x16x32_bf16(pf, ones, lacc, 0, 0, 0);
  }

  // lacc row r == query quad*4+r == o0/o1 row r (all 16 cols identical)
  const int orow = b * TSEQ + q0 + quad * 4;
#pragma unroll
  for (int r = 0; r < 4; ++r) {
    const float linv = 1.0f / lacc[r];
    outp[(size_t)(orow + r) * DIM + h * HDIM + col]      = f2bf(o0[r] * linv);
    outp[(size_t)(orow + r) * DIM + h * HDIM + 16 + col] = f2bf(o1[r] * linv);
  }
}

// --------------------------------------------------------------- layernorm
__global__ __launch_bounds__(256) void ln_kernel(
    const float* __restrict__ xin, const float* __restrict__ proj,
    const float* __restrict__ gs, const float* __restrict__ gb,
    float* __restrict__ xoutf, short* __restrict__ xoutb)
{
  const int wave = threadIdx.x >> 6, lane = threadIdx.x & 63;
  const int row = blockIdx.x * 4 + wave;
  const float4 xv = *(const float4*)(xin + (size_t)row * DIM + lane * 4);
  const float4 pv = *(const float4*)(proj + (size_t)row * DIM + lane * 4);
  const float y0 = xv.x + pv.x, y1 = xv.y + pv.y, y2 = xv.z + pv.z, y3 = xv.w + pv.w;
  float s = y0 + y1 + y2 + y3;
  float q = y0 * y0 + y1 * y1 + y2 * y2 + y3 * y3;
#pragma unroll
  for (int o = 1; o < 64; o <<= 1) { s += __shfl_xor(s, o); q += __shfl_xor(q, o); }
  const float mu = s * (1.0f / DIM);
  const float var = q * (1.0f / DIM) - mu * mu;
  const float rstd = rsqrtf(var + 1e-5f);
  const float4 sv = *(const float4*)(gs + lane * 4);
  const float4 bv = *(const float4*)(gb + lane * 4);
  const float o0 = (y0 - mu) * rstd * sv.x + bv.x;
  const float o1 = (y1 - mu) * rstd * sv.y + bv.y;
  const float o2 = (y2 - mu) * rstd * sv.z + bv.z;
  const float o3 = (y3 - mu) * rstd * sv.w + bv.w;
  *(float4*)(xoutf + (size_t)row * DIM + lane * 4) = make_float4(o0, o1, o2, o3);
  short4 pk; pk.x = f2bf(o0); pk.y = f2bf(o1); pk.z = f2bf(o2); pk.w = f2bf(o3);
  *(short4*)(xoutb + (size_t)row * DIM + lane * 4) = pk;
}

// ------------------------------------------------------------------ launch
extern "C" void kernel_launch(void* const* d_in, const int* in_sizes, int n_in,
                              void* d_out, int out_size, void* d_ws, size_t ws_size,
                              hipStream_t stream)
{
  const float* rows = (const float*)d_in[0];
  const float* tte  = (const float*)d_in[1];
  const float* Wq = (const float*)d_in[2];  const float* bq = (const float*)d_in[3];
  const float* Wk = (const float*)d_in[4];  const float* bk = (const float*)d_in[5];
  const float* Wv = (const float*)d_in[6];  const float* bv = (const float*)d_in[7];
  const float* Wo = (const float*)d_in[8];  const float* bo = (const float*)d_in[9];
  const float* W1 = (const float*)d_in[10]; const float* b1 = (const float*)d_in[11];
  const float* W2 = (const float*)d_in[12]; const float* b2 = (const float*)d_in[13];
  const float* ln1s = (const float*)d_in[14]; const float* ln1b = (const float*)d_in[15];
  const float* ln2s = (const float*)d_in[16]; const float* ln2b = (const float*)d_in[17];

  char* p = (char*)d_ws;
  float* xf   = (float*)p;  p += (size_t)MROWS * DIM * 4;
  short* xb   = (short*)p;  p += (size_t)MROWS * DIM * 2;
  short* qkv  = (short*)p;  p += (size_t)MROWS * 768 * 2;
  short* vtb  = (short*)p;  p += (size_t)BATCH * DIM * TSEQ * 2;
  short* ob   = (short*)p;  p += (size_t)MROWS * DIM * 2;
  float* tmpf = (float*)p;  p += (size_t)MROWS * DIM * 4;
  short* hb   = (short*)p;  p += (size_t)MROWS * FFDIM * 2;
  short* qkvT = (short*)p;  p += (size_t)NLAYER * 768 * DIM * 2;
  short* woT  = (short*)p;  p += (size_t)NLAYER * DIM * DIM * 2;
  short* w1T  = (short*)p;  p += (size_t)NLAYER * FFDIM * DIM * 2;
  short* w2T  = (short*)p;  p += (size_t)NLAYER * DIM * FFDIM * 2;

  prep_w<<<2048, 256, 0, stream>>>(Wq, Wk, Wv, Wo, W1, W2, qkvT, woT, w1T, w2T);
  prep_x<<<MROWS * DIM / 4 / 256, 256, 0, stream>>>(rows, tte, xf, xb);

  for (int l = 0; l < NLAYER; ++l) {
    gemm_bt<1><<<dim3(MROWS / GBM, 768 / GBN), 256, 0, stream>>>(
        xb, qkvT + (size_t)l * 768 * DIM, bq + l * DIM, bk + l * DIM, bv + l * DIM,
        qkv, MROWS, 768, DIM);
    transpose_v<<<dim3(TSEQ / 32, DIM / 32, BATCH), 256, 0, stream>>>(qkv, vtb);
    attn_kernel<<<dim3(TSEQ / 64, BATCH * NHEAD), 256, 0, stream>>>(qkv, vtb, ob);
    gemm_bt<2><<<dim3(MROWS / GBM, DIM / GBN), 256, 0, stream>>>(
        ob, woT + (size_t)l * DIM * DIM, bo + l * DIM, nullptr, nullptr,
        tmpf, MROWS, DIM, DIM);
    ln_kernel<<<MROWS / 4, 256, 0, stream>>>(xf, tmpf, ln1s + l * DIM, ln1b + l * DIM, xf, xb);
    gemm_bt<3><<<dim3(MROWS / GBM, FFDIM / GBN), 256, 0, stream>>>(
        xb, w1T + (size_t)l * FFDIM * DIM, b1 + l * FFDIM, nullptr, nullptr,
        hb, MROWS, FFDIM, DIM);
    gemm_bt<2><<<dim3(MROWS / GBM, DIM / GBN), 256, 0, stream>>>(
        hb, w2T + (size_t)l * DIM * FFDIM, b2 + l * DIM, nullptr, nullptr,
        tmpf, MROWS, DIM, FFDIM);
    float* xo = (l == NLAYER - 1) ? (float*)d_out : xf;
    ln_kernel<<<MROWS / 4, 256, 0, stream>>>(xf, tmpf, ln2s + l * DIM, ln2b + l * DIM, xo, xb);
  }
}

// Round 4
// 541.269 us; speedup vs baseline: 1.5946x; 1.5946x over previous
//
#include <hip/hip_runtime.h>
#include <cstdint>
#include <cstddef>

#define TSEQ 4096
#define BATCH 2
#define DIM 256
#define NHEAD 8
#define HDIM 32
#define NLAYER 4
#define FFDIM 1024
#define SPLITN 2048
#define MROWS (BATCH * TSEQ)   // 8192

// (1/sqrt(HD)) * log2(e)  -- folded into q at the QKV epilogue so softmax uses exp2 directly
#define QSCALE 0.2550784545f

typedef __attribute__((ext_vector_type(4))) float f32x4;
typedef __attribute__((ext_vector_type(8))) short bf16x8;

__device__ __forceinline__ short f2bf(float f) {
  union { float f; uint32_t u; } v; v.f = f;
  uint32_t r = v.u + 0x7fffu + ((v.u >> 16) & 1u);
  return (short)(r >> 16);
}

// raw v_exp_f32 -- inputs here are bounded, no libm range fixup needed
__device__ __forceinline__ float fast_exp2(float x) {
#if __has_builtin(__builtin_amdgcn_exp2f)
  return __builtin_amdgcn_exp2f(x);
#else
  float r;
  asm volatile("v_exp_f32 %0, %1\n\ts_nop 1" : "=v"(r) : "v"(x));
  return r;
#endif
}

// pack two fp32 -> two bf16 (round-half-up; 3 VALU ops)
__device__ __forceinline__ uint32_t pack2bf(float a, float b) {
  union { float f; uint32_t u; } ua, ub; ua.f = a; ub.f = b;
  return ((ua.u + 0x8000u) >> 16) | ((ub.u + 0x8000u) & 0xffff0000u);
}

__device__ __forceinline__ float gelu_f(float x) {
  float u = 0.7978845608f * x * (1.0f + 0.044715f * x * x);
  u = fminf(fmaxf(u, -20.f), 20.f);
  float e = fast_exp2(2.885390082f * u);   // exp(2u)
  float t = (e - 1.0f) / (e + 1.0f);
  return 0.5f * x * (1.0f + t);
}

#define AS1 __attribute__((address_space(1)))
#define AS3 __attribute__((address_space(3)))
__device__ __forceinline__ void gload16(const void* g, void* l) {
  __builtin_amdgcn_global_load_lds((AS1 void*)g, (AS3 void*)l, 16, 0, 0);
}

// ---------------------------------------------------------------- weight prep
__global__ __launch_bounds__(256) void prep_w(
    const float* __restrict__ Wq, const float* __restrict__ Wk,
    const float* __restrict__ Wv, const float* __restrict__ Wo,
    const float* __restrict__ W1, const float* __restrict__ W2,
    short* __restrict__ qkvT, short* __restrict__ woT,
    short* __restrict__ w1T, short* __restrict__ w2T)
{
  const int NQKV = NLAYER * 768 * DIM;   // 786432
  const int NO   = NLAYER * DIM * DIM;   // 262144
  const int NF   = NLAYER * FFDIM * DIM; // 1048576
  const int total = NQKV + NO + 2 * NF;
  for (int idx = blockIdx.x * 256 + threadIdx.x; idx < total; idx += gridDim.x * 256) {
    if (idx < NQKV) {                       // qkvT[l][n:768][k:256]
      const int l = idx / (768 * DIM);
      const int rem = idx - l * 768 * DIM;
      const int n = rem >> 8, k = rem & 255;
      const float* src = (n < 256) ? Wq : ((n < 512) ? Wk : Wv);
      qkvT[idx] = f2bf(src[((size_t)l * DIM + k) * DIM + (n & 255)]);
    } else if (idx < NQKV + NO) {           // woT[l][n:256][k:256]
      const int j = idx - NQKV;
      const int l = j >> 16;
      const int rem = j & 65535;
      const int n = rem >> 8, k = rem & 255;
      woT[j] = f2bf(Wo[((size_t)l * DIM + k) * DIM + n]);
    } else if (idx < NQKV + NO + NF) {      // w1T[l][n:1024][k:256]
      const int j = idx - NQKV - NO;
      const int l = j >> 18;
      const int rem = j & 262143;
      const int n = rem >> 8, k = rem & 255;
      w1T[j] = f2bf(W1[((size_t)l * DIM + k) * FFDIM + n]);
    } else {                                // w2T[l][n:256][k:1024]
      const int j = idx - NQKV - NO - NF;
      const int l = j >> 18;
      const int rem = j & 262143;
      const int n = rem >> 10, k = rem & 1023;
      w2T[j] = f2bf(W2[((size_t)l * FFDIM + k) * DIM + n]);
    }
  }
}

// ------------------------------------------------------------------- x prep
__global__ __launch_bounds__(256) void prep_x(
    const float* __restrict__ rows, const float* __restrict__ tte,
    float* __restrict__ xf, short* __restrict__ xb)
{
  const size_t idx = (size_t)blockIdx.x * 256 + threadIdx.x;  // float4 index
  float4 v = ((const float4*)rows)[idx];
  const size_t e = idx * 4;
  const int m = (int)(e >> 8);
  const int d = (int)(e & 255);
  const int t = m & (TSEQ - 1);
  const int bb = m >> 12;
  if (t < SPLITN) {
    const float4 a = ((const float4*)tte)[((size_t)bb * SPLITN + t) * (DIM / 4) + (d >> 2)];
    v.x += a.x; v.y += a.y; v.z += a.z; v.w += a.w;
  }
  ((float4*)xf)[idx] = v;
  short4 pk; pk.x = f2bf(v.x); pk.y = f2bf(v.y); pk.z = f2bf(v.z); pk.w = f2bf(v.w);
  ((short4*)xb)[idx] = pk;
}

// ---------------------------------------------------------------------- GEMM
#define GBM 128
#define GBN 64
#define GBK 64

template<int EPI>
__global__ __launch_bounds__(256, 4) void gemm_bt(
    const short* __restrict__ A, const short* __restrict__ BT,
    const float* __restrict__ bias0, const float* __restrict__ bias1,
    const float* __restrict__ bias2, void* __restrict__ Cout,
    int M, int N, int K)
{
  __shared__ short As[GBM * GBK];
  __shared__ short Bs[GBN * GBK];
  const int tid = threadIdx.x;
  const int lane = tid & 63;
  const int wave = tid >> 6;
  const int wm = wave & 1, wn = wave >> 1;
  const int col = lane & 15, quad = lane >> 4;

  const short* Ab = A + (size_t)blockIdx.x * GBM * K;
  const short* Bb = BT + (size_t)blockIdx.y * GBN * K;

  const f32x4 fz = {0.f, 0.f, 0.f, 0.f};
  f32x4 acc[4][2];
#pragma unroll
  for (int i = 0; i < 4; ++i)
#pragma unroll
    for (int j = 0; j < 2; ++j) acc[i][j] = fz;

  for (int k0 = 0; k0 < K; k0 += GBK) {
#pragma unroll
    for (int p = 0; p < 4; ++p) {
      int i = p * 256 + tid;
      gload16(Ab + (size_t)(i >> 3) * K + k0 + (i & 7) * 8, &As[i * 8]);
    }
#pragma unroll
    for (int p = 0; p < 2; ++p) {
      int i = p * 256 + tid;
      gload16(Bb + (size_t)(i >> 3) * K + k0 + (i & 7) * 8, &Bs[i * 8]);
    }
    __syncthreads();
#pragma unroll
    for (int ks = 0; ks < GBK; ks += 32) {
      bf16x8 af[4], bfr[2];
#pragma unroll
      for (int tm = 0; tm < 4; ++tm)
        af[tm] = *(const bf16x8*)&As[(wm * 64 + tm * 16 + col) * GBK + ks + quad * 8];
#pragma unroll
      for (int tn = 0; tn < 2; ++tn)
        bfr[tn] = *(const bf16x8*)&Bs[(wn * 32 + tn * 16 + col) * GBK + ks + quad * 8];
#pragma unroll
      for (int tm = 0; tm < 4; ++tm)
#pragma unroll
        for (int tn = 0; tn < 2; ++tn)
          acc[tm][tn] = __builtin_amdgcn_mfma_f32_16x16x32_bf16(af[tm], bfr[tn], acc[tm][tn], 0, 0, 0);
    }
    __syncthreads();
  }

#pragma unroll
  for (int tm = 0; tm < 4; ++tm) {
    const int mbase = blockIdx.x * GBM + wm * 64 + tm * 16 + quad * 4;
#pragma unroll
    for (int tn = 0; tn < 2; ++tn) {
      const int n = blockIdx.y * GBN + wn * 32 + tn * 16 + col;
      float bv;
      if (EPI == 1) bv = (n < 256) ? bias0[n] : ((n < 512) ? bias1[n - 256] : bias2[n - 512]);
      else          bv = bias0[n];
#pragma unroll
      for (int r = 0; r < 4; ++r) {
        float v = acc[tm][tn][r] + bv;
        size_t off = (size_t)(mbase + r) * N + n;
        if (EPI == 1) {
          if (n < 256) v *= QSCALE;
          ((short*)Cout)[off] = f2bf(v);
        } else if (EPI == 2) {
          ((float*)Cout)[off] = v;
        } else {
          ((short*)Cout)[off] = f2bf(gelu_f(v));
        }
      }
    }
  }
}

// ------------------------------------------------------------- V transpose
__global__ __launch_bounds__(256) void transpose_v(
    const short* __restrict__ qkv, short* __restrict__ vt)
{
  __shared__ short tile[32][33];
  const int t0 = blockIdx.x * 32;
  const int c0 = blockIdx.y * 32;
  const int b = blockIdx.z;
  const int tx = threadIdx.x & 31, ty = threadIdx.x >> 5;
#pragma unroll
  for (int i = 0; i < 4; ++i) {
    const int t = t0 + ty + i * 8;
    tile[ty + i * 8][tx] = qkv[(size_t)(b * TSEQ + t) * 768 + 512 + c0 + tx];
  }
  __syncthreads();
#pragma unroll
  for (int i = 0; i < 4; ++i) {
    const int c = c0 + ty + i * 8;
    vt[(size_t)(b * DIM + c) * TSEQ + t0 + tx] = tile[tx][ty + i * 8];
  }
}

// ----------------------------------------------------------------- attention
// Block = 128 queries of one (b,h); 4 waves x 32 queries (2 subtiles of 16).
// K/V staged cooperatively into LDS via global_load_lds (64-key tiles,
// 2 buffers, 1 barrier per tile: DMA for tile i+1 streams during compute i).
// V staged with XOR granule swizzle (pos = g ^ (hd&7)) so B-frag b128 reads
// hit the conflict-free floor.  P round-trips per-wave LDS (lgkm fence only).
#define AKT 64   // keys per tile

__global__ __launch_bounds__(256, 4) void attn_kernel(
    const short* __restrict__ qkv, const short* __restrict__ vt,
    short* __restrict__ outp)
{
  __shared__ short Kbuf[2][AKT * HDIM];        // [key][hd]        4 KB x2
  __shared__ short Vbuf[2][HDIM * AKT];        // [hd][key-gran-swz] 4 KB x2
  __shared__ short Pall[4][32][72];            // per-wave P, padded rows

  const int tid = threadIdx.x;
  const int lane = tid & 63;
  const int wave = tid >> 6;
  const int col = lane & 15, quad = lane >> 4;
  const int bh = blockIdx.y;
  const int b = bh >> 3, h = bh & 7;
  const int q0 = blockIdx.x * 128 + wave * 32;   // this wave's 32 queries

  short (*P)[72] = Pall[wave];

  const short* qbase = qkv + (size_t)b * TSEQ * 768 + h * HDIM;        // q cols
  const short* kbase = qbase + 256;                                    // k cols
  const short* vtb = vt + (size_t)bh * HDIM * TSEQ;

  // staging source addresses (per thread, constant across tiles except k0)
  const short* ksrc = kbase + (size_t)(tid >> 2) * 768 + (tid & 3) * 8;
  const short* vsrc = vtb + (size_t)(tid >> 3) * TSEQ + (((tid & 7) ^ ((tid >> 3) & 7)) * 8);

  // Q B-fragments for the two 16-query subtiles
  const bf16x8 qf0 = *(const bf16x8*)(qbase + (size_t)(q0 + col) * 768 + quad * 8);
  const bf16x8 qf1 = *(const bf16x8*)(qbase + (size_t)(q0 + 16 + col) * 768 + quad * 8);

  bf16x8 ones;
#pragma unroll
  for (int i = 0; i < 8; ++i) ones[i] = (short)0x3F80;  // bf16 1.0

  const f32x4 fz = {0.f, 0.f, 0.f, 0.f};
  f32x4 o[2][2] = {{fz, fz}, {fz, fz}};   // [qsub][hdhalf]
  f32x4 lacc0 = fz, lacc1 = fz;

  // stage tile 0 into buffer 0
  gload16(ksrc, &Kbuf[0][tid * 8]);
  gload16(vsrc, &Vbuf[0][tid * 8]);

  int cur = 0;
  for (int t = 0; t < SPLITN / AKT; ++t) {
    __syncthreads();   // waves drain own vmcnt before barrier -> buf[cur] ready
    if (t + 1 < SPLITN / AKT) {
      const int kn = (t + 1) * AKT;
      gload16(ksrc + (size_t)kn * 768, &Kbuf[1 - cur][tid * 8]);
      gload16(vsrc + kn, &Vbuf[1 - cur][tid * 8]);
    }
    const short* kb = Kbuf[cur];
    const short* vb = Vbuf[cur];

    // ---- S phase: S^T = K·Q^T per 16-key subtile, exp2, pack into P
#pragma unroll
    for (int st = 0; st < 4; ++st) {
      const bf16x8 kf = *(const bf16x8*)&kb[(st * 16 + col) * HDIM + quad * 8];
      const f32x4 s0 = __builtin_amdgcn_mfma_f32_16x16x32_bf16(kf, qf0, fz, 0, 0, 0);
      const f32x4 s1 = __builtin_amdgcn_mfma_f32_16x16x32_bf16(kf, qf1, fz, 0, 0, 0);
      uint2 w0, w1;
      w0.x = pack2bf(fast_exp2(s0[0]), fast_exp2(s0[1]));
      w0.y = pack2bf(fast_exp2(s0[2]), fast_exp2(s0[3]));
      w1.x = pack2bf(fast_exp2(s1[0]), fast_exp2(s1[1]));
      w1.y = pack2bf(fast_exp2(s1[2]), fast_exp2(s1[3]));
      *(uint2*)&P[col][st * 16 + quad * 4] = w0;
      *(uint2*)&P[16 + col][st * 16 + quad * 4] = w1;
    }
    asm volatile("s_waitcnt lgkmcnt(0)" ::: "memory");  // wave-local P fence

    // ---- PV phase: O += P·V, lsum += P·1
#pragma unroll
    for (int kh = 0; kh < 2; ++kh) {
      const bf16x8 pf0 = *(const bf16x8*)&P[col][kh * 32 + quad * 8];
      const bf16x8 pf1 = *(const bf16x8*)&P[16 + col][kh * 32 + quad * 8];
#pragma unroll
      for (int hh = 0; hh < 2; ++hh) {
        const int hd = hh * 16 + col;
        const bf16x8 vf = *(const bf16x8*)&vb[hd * AKT + (((kh * 4 + quad) ^ (hd & 7)) * 8)];
        o[0][hh] = __builtin_amdgcn_mfma_f32_16x16x32_bf16(pf0, vf, o[0][hh], 0, 0, 0);
        o[1][hh] = __builtin_amdgcn_mfma_f32_16x16x32_bf16(pf1, vf, o[1][hh], 0, 0, 0);
      }
      lacc0 = __builtin_amdgcn_mfma_f32_16x16x32_bf16(pf0, ones, lacc0, 0, 0, 0);
      lacc1 = __builtin_amdgcn_mfma_f32_16x16x32_bf16(pf1, ones, lacc1, 0, 0, 0);
    }
    cur ^= 1;
  }

  // ---- diagonal self-key chunk for test-query blocks (block-uniform branch)
  if (blockIdx.x >= SPLITN / 128) {
#pragma unroll
    for (int qsub = 0; qsub < 2; ++qsub) {
      const int qd = q0 + qsub * 16;
      const bf16x8 qf = qsub ? qf1 : qf0;
      const bf16x8 kf = *(const bf16x8*)(kbase + (size_t)(qd + col) * 768 + quad * 8);
      const f32x4 sd = __builtin_amdgcn_mfma_f32_16x16x32_bf16(kf, qf, fz, 0, 0, 0);
      float pd[4];
#pragma unroll
      for (int r = 0; r < 4; ++r)
        pd[r] = (quad * 4 + r) == col ? fast_exp2(sd[r]) : 0.f;
      uint2 w0, wz; wz.x = 0; wz.y = 0;
      w0.x = pack2bf(pd[0], pd[1]); w0.y = pack2bf(pd[2], pd[3]);
      *(uint2*)&P[qsub * 16 + col][quad * 4] = w0;
      *(uint2*)&P[qsub * 16 + col][16 + quad * 4] = wz;
    }
    asm volatile("s_waitcnt lgkmcnt(0)" ::: "memory");
#pragma unroll
    for (int qsub = 0; qsub < 2; ++qsub) {
      const int qd = q0 + qsub * 16;
      const bf16x8 pf = *(const bf16x8*)&P[qsub * 16 + col][quad * 8];
#pragma unroll
      for (int hh = 0; hh < 2; ++hh) {
        // quads 2,3 read keys qd+16..31 (in-bounds garbage) x P==0
        const bf16x8 vf = *(const bf16x8*)(vtb + (size_t)(hh * 16 + col) * TSEQ + qd + quad * 8);
        o[qsub][hh] = __builtin_amdgcn_mfma_f32_16x16x32_bf16(pf, vf, o[qsub][hh], 0, 0, 0);
      }
      if (qsub == 0) lacc0 = __builtin_amdgcn_mfma_f32_16x16x32_bf16(pf, ones, lacc0, 0, 0, 0);
      else           lacc1 = __builtin_amdgcn_mfma_f32_16x16x32_bf16(pf, ones, lacc1, 0, 0, 0);
    }
  }

  // ---- epilogue: normalize and store (C-layout rows = quad*4+r)
#pragma unroll
  for (int qsub = 0; qsub < 2; ++qsub) {
    const f32x4 la = qsub ? lacc1 : lacc0;
    const int rowb = b * TSEQ + q0 + qsub * 16 + quad * 4;
#pragma unroll
    for (int r = 0; r < 4; ++r) {
      const float linv = 1.0f / la[r];
#pragma unroll
      for (int hh = 0; hh < 2; ++hh)
        outp[(size_t)(rowb + r) * DIM + h * HDIM + hh * 16 + col] = f2bf(o[qsub][hh][r] * linv);
    }
  }
}

// --------------------------------------------------------------- layernorm
__global__ __launch_bounds__(256) void ln_kernel(
    const float* __restrict__ xin, const float* __restrict__ proj,
    const float* __restrict__ gs, const float* __restrict__ gb,
    float* __restrict__ xoutf, short* __restrict__ xoutb)
{
  const int wave = threadIdx.x >> 6, lane = threadIdx.x & 63;
  const int row = blockIdx.x * 4 + wave;
  const float4 xv = *(const float4*)(xin + (size_t)row * DIM + lane * 4);
  const float4 pv = *(const float4*)(proj + (size_t)row * DIM + lane * 4);
  const float y0 = xv.x + pv.x, y1 = xv.y + pv.y, y2 = xv.z + pv.z, y3 = xv.w + pv.w;
  float s = y0 + y1 + y2 + y3;
  float q = y0 * y0 + y1 * y1 + y2 * y2 + y3 * y3;
#pragma unroll
  for (int o = 1; o < 64; o <<= 1) { s += __shfl_xor(s, o); q += __shfl_xor(q, o); }
  const float mu = s * (1.0f / DIM);
  const float var = q * (1.0f / DIM) - mu * mu;
  const float rstd = rsqrtf(var + 1e-5f);
  const float4 sv = *(const float4*)(gs + lane * 4);
  const float4 bv = *(const float4*)(gb + lane * 4);
  const float o0 = (y0 - mu) * rstd * sv.x + bv.x;
  const float o1 = (y1 - mu) * rstd * sv.y + bv.y;
  const float o2 = (y2 - mu) * rstd * sv.z + bv.z;
  const float o3 = (y3 - mu) * rstd * sv.w + bv.w;
  *(float4*)(xoutf + (size_t)row * DIM + lane * 4) = make_float4(o0, o1, o2, o3);
  short4 pk; pk.x = f2bf(o0); pk.y = f2bf(o1); pk.z = f2bf(o2); pk.w = f2bf(o3);
  *(short4*)(xoutb + (size_t)row * DIM + lane * 4) = pk;
}

// ------------------------------------------------------------------ launch
extern "C" void kernel_launch(void* const* d_in, const int* in_sizes, int n_in,
                              void* d_out, int out_size, void* d_ws, size_t ws_size,
                              hipStream_t stream)
{
  const float* rows = (const float*)d_in[0];
  const float* tte  = (const float*)d_in[1];
  const float* Wq = (const float*)d_in[2];  const float* bq = (const float*)d_in[3];
  const float* Wk = (const float*)d_in[4];  const float* bk = (const float*)d_in[5];
  const float* Wv = (const float*)d_in[6];  const float* bv = (const float*)d_in[7];
  const float* Wo = (const float*)d_in[8];  const float* bo = (const float*)d_in[9];
  const float* W1 = (const float*)d_in[10]; const float* b1 = (const float*)d_in[11];
  const float* W2 = (const float*)d_in[12]; const float* b2 = (const float*)d_in[13];
  const float* ln1s = (const float*)d_in[14]; const float* ln1b = (const float*)d_in[15];
  const float* ln2s = (const float*)d_in[16]; const float* ln2b = (const float*)d_in[17];

  char* p = (char*)d_ws;
  float* xf   = (float*)p;  p += (size_t)MROWS * DIM * 4;
  short* xb   = (short*)p;  p += (size_t)MROWS * DIM * 2;
  short* qkv  = (short*)p;  p += (size_t)MROWS * 768 * 2;
  short* vtb  = (short*)p;  p += (size_t)BATCH * DIM * TSEQ * 2;
  short* ob   = (short*)p;  p += (size_t)MROWS * DIM * 2;
  float* tmpf = (float*)p;  p += (size_t)MROWS * DIM * 4;
  short* hb   = (short*)p;  p += (size_t)MROWS * FFDIM * 2;
  short* qkvT = (short*)p;  p += (size_t)NLAYER * 768 * DIM * 2;
  short* woT  = (short*)p;  p += (size_t)NLAYER * DIM * DIM * 2;
  short* w1T  = (short*)p;  p += (size_t)NLAYER * FFDIM * DIM * 2;
  short* w2T  = (short*)p;  p += (size_t)NLAYER * DIM * FFDIM * 2;

  prep_w<<<2048, 256, 0, stream>>>(Wq, Wk, Wv, Wo, W1, W2, qkvT, woT, w1T, w2T);
  prep_x<<<MROWS * DIM / 4 / 256, 256, 0, stream>>>(rows, tte, xf, xb);

  for (int l = 0; l < NLAYER; ++l) {
    gemm_bt<1><<<dim3(MROWS / GBM, 768 / GBN), 256, 0, stream>>>(
        xb, qkvT + (size_t)l * 768 * DIM, bq + l * DIM, bk + l * DIM, bv + l * DIM,
        qkv, MROWS, 768, DIM);
    transpose_v<<<dim3(TSEQ / 32, DIM / 32, BATCH), 256, 0, stream>>>(qkv, vtb);
    attn_kernel<<<dim3(TSEQ / 128, BATCH * NHEAD), 256, 0, stream>>>(qkv, vtb, ob);
    gemm_bt<2><<<dim3(MROWS / GBM, DIM / GBN), 256, 0, stream>>>(
        ob, woT + (size_t)l * DIM * DIM, bo + l * DIM, nullptr, nullptr,
        tmpf, MROWS, DIM, DIM);
    ln_kernel<<<MROWS / 4, 256, 0, stream>>>(xf, tmpf, ln1s + l * DIM, ln1b + l * DIM, xf, xb);
    gemm_bt<3><<<dim3(MROWS / GBM, FFDIM / GBN), 256, 0, stream>>>(
        xb, w1T + (size_t)l * FFDIM * DIM, b1 + l * FFDIM, nullptr, nullptr,
        hb, MROWS, FFDIM, DIM);
    gemm_bt<2><<<dim3(MROWS / GBM, DIM / GBN), 256, 0, stream>>>(
        hb, w2T + (size_t)l * DIM * FFDIM, b2 + l * DIM, nullptr, nullptr,
        tmpf, MROWS, DIM, FFDIM);
    float* xo = (l == NLAYER - 1) ? (float*)d_out : xf;
    ln_kernel<<<MROWS / 4, 256, 0, stream>>>(xf, tmpf, ln2s + l * DIM, ln2b + l * DIM, xo, xb);
  }
}

// Round 5
// 530.160 us; speedup vs baseline: 1.6280x; 1.0210x over previous
//
#include <hip/hip_runtime.h>
#include <cstdint>
#include <cstddef>

#define TSEQ 4096
#define BATCH 2
#define DIM 256
#define NHEAD 8
#define HDIM 32
#define NLAYER 4
#define FFDIM 1024
#define SPLITN 2048
#define MROWS (BATCH * TSEQ)   // 8192

// (1/sqrt(HD)) * log2(e)  -- folded into q at the QKV epilogue so softmax uses exp2 directly
#define QSCALE 0.2550784545f

typedef __attribute__((ext_vector_type(4))) float f32x4;
typedef __attribute__((ext_vector_type(8))) short bf16x8;

__device__ __forceinline__ short f2bf(float f) {
  union { float f; uint32_t u; } v; v.f = f;
  uint32_t r = v.u + 0x7fffu + ((v.u >> 16) & 1u);
  return (short)(r >> 16);
}

__device__ __forceinline__ float fast_exp2(float x) {
#if __has_builtin(__builtin_amdgcn_exp2f)
  return __builtin_amdgcn_exp2f(x);
#else
  float r;
  asm volatile("v_exp_f32 %0, %1\n\ts_nop 1" : "=v"(r) : "v"(x));
  return r;
#endif
}

// pack two fp32 -> two bf16 (round-half-up; 3 VALU ops)
__device__ __forceinline__ uint32_t pack2bf(float a, float b) {
  union { float f; uint32_t u; } ua, ub; ua.f = a; ub.f = b;
  return ((ua.u + 0x8000u) >> 16) | ((ub.u + 0x8000u) & 0xffff0000u);
}

__device__ __forceinline__ float gelu_f(float x) {
  float u = 0.7978845608f * x * (1.0f + 0.044715f * x * x);
  u = fminf(fmaxf(u, -20.f), 20.f);
  float e = fast_exp2(2.885390082f * u);   // exp(2u)
  float t = (e - 1.0f) / (e + 1.0f);
  return 0.5f * x * (1.0f + t);
}

#define AS1 __attribute__((address_space(1)))
#define AS3 __attribute__((address_space(3)))
__device__ __forceinline__ void gload16(const void* g, void* l) {
  __builtin_amdgcn_global_load_lds((AS1 void*)g, (AS3 void*)l, 16, 0, 0);
}

// ---------------------------------------------------------------- weight prep
__global__ __launch_bounds__(256) void prep_w(
    const float* __restrict__ Wq, const float* __restrict__ Wk,
    const float* __restrict__ Wv, const float* __restrict__ Wo,
    const float* __restrict__ W1, const float* __restrict__ W2,
    short* __restrict__ qkvT, short* __restrict__ woT,
    short* __restrict__ w1T, short* __restrict__ w2T)
{
  const int NQKV = NLAYER * 768 * DIM;
  const int NO   = NLAYER * DIM * DIM;
  const int NF   = NLAYER * FFDIM * DIM;
  const int total = NQKV + NO + 2 * NF;
  for (int idx = blockIdx.x * 256 + threadIdx.x; idx < total; idx += gridDim.x * 256) {
    if (idx < NQKV) {                       // qkvT[l][n:768][k:256]
      const int l = idx / (768 * DIM);
      const int rem = idx - l * 768 * DIM;
      const int n = rem >> 8, k = rem & 255;
      const float* src = (n < 256) ? Wq : ((n < 512) ? Wk : Wv);
      qkvT[idx] = f2bf(src[((size_t)l * DIM + k) * DIM + (n & 255)]);
    } else if (idx < NQKV + NO) {           // woT[l][n:256][k:256]
      const int j = idx - NQKV;
      const int l = j >> 16;
      const int rem = j & 65535;
      const int n = rem >> 8, k = rem & 255;
      woT[j] = f2bf(Wo[((size_t)l * DIM + k) * DIM + n]);
    } else if (idx < NQKV + NO + NF) {      // w1T[l][n:1024][k:256]
      const int j = idx - NQKV - NO;
      const int l = j >> 18;
      const int rem = j & 262143;
      const int n = rem >> 8, k = rem & 255;
      w1T[j] = f2bf(W1[((size_t)l * DIM + k) * FFDIM + n]);
    } else {                                // w2T[l][n:256][k:1024]
      const int j = idx - NQKV - NO - NF;
      const int l = j >> 18;
      const int rem = j & 262143;
      const int n = rem >> 10, k = rem & 1023;
      w2T[j] = f2bf(W2[((size_t)l * FFDIM + k) * DIM + n]);
    }
  }
}

// ------------------------------------------------------------------- x prep
__global__ __launch_bounds__(256) void prep_x(
    const float* __restrict__ rows, const float* __restrict__ tte,
    float* __restrict__ xf, short* __restrict__ xb)
{
  const size_t idx = (size_t)blockIdx.x * 256 + threadIdx.x;  // float4 index
  float4 v = ((const float4*)rows)[idx];
  const size_t e = idx * 4;
  const int m = (int)(e >> 8);
  const int d = (int)(e & 255);
  const int t = m & (TSEQ - 1);
  const int bb = m >> 12;
  if (t < SPLITN) {
    const float4 a = ((const float4*)tte)[((size_t)bb * SPLITN + t) * (DIM / 4) + (d >> 2)];
    v.x += a.x; v.y += a.y; v.z += a.z; v.w += a.w;
  }
  ((float4*)xf)[idx] = v;
  short4 pk; pk.x = f2bf(v.x); pk.y = f2bf(v.y); pk.z = f2bf(v.z); pk.w = f2bf(v.w);
  ((short4*)xb)[idx] = pk;
}

// ---------------------------------------------------------------------- GEMM
// (m97 pattern, unchanged)  EPI: 1=qkv (+bias, q scaled, bf16)  3=gelu bf16
#define GBM 128
#define GBN 64
#define GBK 64

template<int EPI>
__global__ __launch_bounds__(256, 4) void gemm_bt(
    const short* __restrict__ A, const short* __restrict__ BT,
    const float* __restrict__ bias0, const float* __restrict__ bias1,
    const float* __restrict__ bias2, void* __restrict__ Cout,
    int M, int N, int K)
{
  __shared__ short As[GBM * GBK];
  __shared__ short Bs[GBN * GBK];
  const int tid = threadIdx.x;
  const int lane = tid & 63;
  const int wave = tid >> 6;
  const int wm = wave & 1, wn = wave >> 1;
  const int col = lane & 15, quad = lane >> 4;

  const short* Ab = A + (size_t)blockIdx.x * GBM * K;
  const short* Bb = BT + (size_t)blockIdx.y * GBN * K;

  const f32x4 fz = {0.f, 0.f, 0.f, 0.f};
  f32x4 acc[4][2];
#pragma unroll
  for (int i = 0; i < 4; ++i)
#pragma unroll
    for (int j = 0; j < 2; ++j) acc[i][j] = fz;

  for (int k0 = 0; k0 < K; k0 += GBK) {
#pragma unroll
    for (int p = 0; p < 4; ++p) {
      int i = p * 256 + tid;
      gload16(Ab + (size_t)(i >> 3) * K + k0 + (i & 7) * 8, &As[i * 8]);
    }
#pragma unroll
    for (int p = 0; p < 2; ++p) {
      int i = p * 256 + tid;
      gload16(Bb + (size_t)(i >> 3) * K + k0 + (i & 7) * 8, &Bs[i * 8]);
    }
    __syncthreads();
#pragma unroll
    for (int ks = 0; ks < GBK; ks += 32) {
      bf16x8 af[4], bfr[2];
#pragma unroll
      for (int tm = 0; tm < 4; ++tm)
        af[tm] = *(const bf16x8*)&As[(wm * 64 + tm * 16 + col) * GBK + ks + quad * 8];
#pragma unroll
      for (int tn = 0; tn < 2; ++tn)
        bfr[tn] = *(const bf16x8*)&Bs[(wn * 32 + tn * 16 + col) * GBK + ks + quad * 8];
#pragma unroll
      for (int tm = 0; tm < 4; ++tm)
#pragma unroll
        for (int tn = 0; tn < 2; ++tn)
          acc[tm][tn] = __builtin_amdgcn_mfma_f32_16x16x32_bf16(af[tm], bfr[tn], acc[tm][tn], 0, 0, 0);
    }
    __syncthreads();
  }

#pragma unroll
  for (int tm = 0; tm < 4; ++tm) {
    const int mbase = blockIdx.x * GBM + wm * 64 + tm * 16 + quad * 4;
#pragma unroll
    for (int tn = 0; tn < 2; ++tn) {
      const int n = blockIdx.y * GBN + wn * 32 + tn * 16 + col;
      float bv;
      if (EPI == 1) bv = (n < 256) ? bias0[n] : ((n < 512) ? bias1[n - 256] : bias2[n - 512]);
      else          bv = bias0[n];
#pragma unroll
      for (int r = 0; r < 4; ++r) {
        float v = acc[tm][tn][r] + bv;
        size_t off = (size_t)(mbase + r) * N + n;
        if (EPI == 1) {
          if (n < 256) v *= QSCALE;
          ((short*)Cout)[off] = f2bf(v);
        } else {
          ((short*)Cout)[off] = f2bf(gelu_f(v));
        }
      }
    }
  }
}

// ------------------------------------------------ GEMM + residual + LN fused
// C = A@BT^T + bias (N=256 full width), out = LN(xres + C)*gs + gb.
// M-tile 32, 4 waves: wave w owns cols w*64..+63, all 32 rows.
__global__ __launch_bounds__(256, 3) void gemm_ln(
    const short* __restrict__ A, const short* __restrict__ BT,
    const float* __restrict__ bias, const float* __restrict__ xres,
    const float* __restrict__ gs, const float* __restrict__ gb,
    float* __restrict__ xoutf, short* __restrict__ xoutb, int K)
{
  __shared__ short As[32 * 64];
  __shared__ short Bs[256 * 64];
  __shared__ float ssum[4][32], ssq[4][32];
  const int tid = threadIdx.x;
  const int lane = tid & 63;
  const int wave = tid >> 6;
  const int col = lane & 15, quad = lane >> 4;
  const int m0 = blockIdx.x * 32;
  const short* Ab = A + (size_t)m0 * K;

  const f32x4 fz = {0.f, 0.f, 0.f, 0.f};
  f32x4 acc[2][4];
#pragma unroll
  for (int i = 0; i < 2; ++i)
#pragma unroll
    for (int j = 0; j < 4; ++j) acc[i][j] = fz;

  for (int k0 = 0; k0 < K; k0 += 64) {
    gload16(Ab + (size_t)(tid >> 3) * K + k0 + (tid & 7) * 8, &As[tid * 8]);
#pragma unroll
    for (int p = 0; p < 8; ++p) {
      int i = p * 256 + tid;
      gload16(BT + (size_t)(i >> 3) * K + k0 + (i & 7) * 8, &Bs[i * 8]);
    }
    __syncthreads();
#pragma unroll
    for (int ks = 0; ks < 64; ks += 32) {
      bf16x8 af[2], bfr[4];
#pragma unroll
      for (int tm = 0; tm < 2; ++tm)
        af[tm] = *(const bf16x8*)&As[(tm * 16 + col) * 64 + ks + quad * 8];
#pragma unroll
      for (int tn = 0; tn < 4; ++tn)
        bfr[tn] = *(const bf16x8*)&Bs[(wave * 64 + tn * 16 + col) * 64 + ks + quad * 8];
#pragma unroll
      for (int tm = 0; tm < 2; ++tm)
#pragma unroll
        for (int tn = 0; tn < 4; ++tn)
          acc[tm][tn] = __builtin_amdgcn_mfma_f32_16x16x32_bf16(af[tm], bfr[tn], acc[tm][tn], 0, 0, 0);
    }
    __syncthreads();
  }

  // v = acc + bias + residual
  const float* resb = xres + (size_t)m0 * DIM;
#pragma unroll
  for (int tn = 0; tn < 4; ++tn) {
    const int n = wave * 64 + tn * 16 + col;
    const float bv = bias[n];
#pragma unroll
    for (int tm = 0; tm < 2; ++tm)
#pragma unroll
      for (int r = 0; r < 4; ++r) {
        const int row = tm * 16 + quad * 4 + r;
        acc[tm][tn][r] += bv + resb[(size_t)row * DIM + n];
      }
  }

  // per-row stats: lane partial over tn, col-reduce (lane bits 0..3), cross-wave via LDS
#pragma unroll
  for (int tm = 0; tm < 2; ++tm)
#pragma unroll
    for (int r = 0; r < 4; ++r) {
      float s = 0.f, q = 0.f;
#pragma unroll
      for (int tn = 0; tn < 4; ++tn) { const float v = acc[tm][tn][r]; s += v; q += v * v; }
      s += __shfl_xor(s, 1); q += __shfl_xor(q, 1);
      s += __shfl_xor(s, 2); q += __shfl_xor(q, 2);
      s += __shfl_xor(s, 4); q += __shfl_xor(q, 4);
      s += __shfl_xor(s, 8); q += __shfl_xor(q, 8);
      if (col == 0) { const int row = tm * 16 + quad * 4 + r; ssum[wave][row] = s; ssq[wave][row] = q; }
    }
  __syncthreads();
  if (tid < 32) {
    const float S = ssum[0][tid] + ssum[1][tid] + ssum[2][tid] + ssum[3][tid];
    const float Q = ssq[0][tid] + ssq[1][tid] + ssq[2][tid] + ssq[3][tid];
    const float mu = S * (1.0f / DIM);
    const float var = Q * (1.0f / DIM) - mu * mu;
    ssum[0][tid] = mu;
    ssq[0][tid] = rsqrtf(var + 1e-5f);
  }
  __syncthreads();

#pragma unroll
  for (int tm = 0; tm < 2; ++tm)
#pragma unroll
    for (int tn = 0; tn < 4; ++tn) {
      const int n = wave * 64 + tn * 16 + col;
      const float g = gs[n], bb = gb[n];
#pragma unroll
      for (int r = 0; r < 4; ++r) {
        const int row = tm * 16 + quad * 4 + r;
        const float out = (acc[tm][tn][r] - ssum[0][row]) * ssq[0][row] * g + bb;
        xoutf[(size_t)(m0 + row) * DIM + n] = out;
        xoutb[(size_t)(m0 + row) * DIM + n] = f2bf(out);
      }
    }
}

// ------------------------------------------------------------- V transpose
__global__ __launch_bounds__(256) void transpose_v(
    const short* __restrict__ qkv, short* __restrict__ vt)
{
  __shared__ short tile[32][33];
  const int t0 = blockIdx.x * 32;
  const int c0 = blockIdx.y * 32;
  const int b = blockIdx.z;
  const int tx = threadIdx.x & 31, ty = threadIdx.x >> 5;
#pragma unroll
  for (int i = 0; i < 4; ++i) {
    const int t = t0 + ty + i * 8;
    tile[ty + i * 8][tx] = qkv[(size_t)(b * TSEQ + t) * 768 + 512 + c0 + tx];
  }
  __syncthreads();
#pragma unroll
  for (int i = 0; i < 4; ++i) {
    const int c = c0 + ty + i * 8;
    vt[(size_t)(b * DIM + c) * TSEQ + t0 + tx] = tile[tx][ty + i * 8];
  }
}

// ----------------------------------------------------------------- attention
// Key-split x2: blockIdx.z = key half (1024 keys each).  Block = 128 queries
// of one (b,h); 4 waves x 32 q.  K staged in hd-part PLANES [part][key]
// (conflict-free b128 reads); V staged [hd][key] with XOR granule swizzle.
// Partial un-normalized O (fp32) + partial l -> ws; combine normalizes.
#define AKT 64
#define KSPL 1024

__global__ __launch_bounds__(256, 4) void attn_kernel(
    const short* __restrict__ qkv, const short* __restrict__ vt,
    float* __restrict__ Opart, float* __restrict__ lpart)
{
  __shared__ short Kbuf[2][AKT * HDIM];   // [part(4)][key(64)][8]  4 KB x2
  __shared__ short Vbuf[2][HDIM * AKT];   // [hd][key-swz]          4 KB x2
  __shared__ short Pall[4][32][72];       // per-wave P, padded rows

  const int tid = threadIdx.x;
  const int lane = tid & 63;
  const int wave = tid >> 6;
  const int col = lane & 15, quad = lane >> 4;
  const int bh = blockIdx.y;
  const int b = bh >> 3, h = bh & 7;
  const int hz = blockIdx.z;
  const int q0 = blockIdx.x * 128 + wave * 32;

  short (*P)[72] = Pall[wave];

  const short* qbase = qkv + (size_t)b * TSEQ * 768 + h * HDIM;
  const short* kbase = qbase + 256;
  const short* vtb = vt + (size_t)bh * HDIM * TSEQ;

  // staging sources: K plane layout (thread t -> key t&63, part t>>6)
  const short* ksrc = kbase + (size_t)(hz * KSPL + (tid & 63)) * 768 + (tid >> 6) * 8;
  const short* vsrc = vtb + (size_t)(tid >> 3) * TSEQ + hz * KSPL + (((tid & 7) ^ ((tid >> 3) & 7)) * 8);

  const bf16x8 qf0 = *(const bf16x8*)(qbase + (size_t)(q0 + col) * 768 + quad * 8);
  const bf16x8 qf1 = *(const bf16x8*)(qbase + (size_t)(q0 + 16 + col) * 768 + quad * 8);

  bf16x8 ones;
#pragma unroll
  for (int i = 0; i < 8; ++i) ones[i] = (short)0x3F80;

  const f32x4 fz = {0.f, 0.f, 0.f, 0.f};
  f32x4 o[2][2] = {{fz, fz}, {fz, fz}};
  f32x4 lacc0 = fz, lacc1 = fz;

  gload16(ksrc, &Kbuf[0][tid * 8]);
  gload16(vsrc, &Vbuf[0][tid * 8]);

  int cur = 0;
  for (int t = 0; t < KSPL / AKT; ++t) {
    __syncthreads();
    if (t + 1 < KSPL / AKT) {
      const int kn = (t + 1) * AKT;
      gload16(ksrc + (size_t)kn * 768, &Kbuf[1 - cur][tid * 8]);
      gload16(vsrc + kn, &Vbuf[1 - cur][tid * 8]);
    }
    const short* kb = Kbuf[cur];
    const short* vb = Vbuf[cur];

#pragma unroll
    for (int st = 0; st < 4; ++st) {
      const bf16x8 kf = *(const bf16x8*)&kb[(quad * 64 + st * 16 + col) * 8];  // plane read
      const f32x4 s0 = __builtin_amdgcn_mfma_f32_16x16x32_bf16(kf, qf0, fz, 0, 0, 0);
      const f32x4 s1 = __builtin_amdgcn_mfma_f32_16x16x32_bf16(kf, qf1, fz, 0, 0, 0);
      uint2 w0, w1;
      w0.x = pack2bf(fast_exp2(s0[0]), fast_exp2(s0[1]));
      w0.y = pack2bf(fast_exp2(s0[2]), fast_exp2(s0[3]));
      w1.x = pack2bf(fast_exp2(s1[0]), fast_exp2(s1[1]));
      w1.y = pack2bf(fast_exp2(s1[2]), fast_exp2(s1[3]));
      *(uint2*)&P[col][st * 16 + quad * 4] = w0;
      *(uint2*)&P[16 + col][st * 16 + quad * 4] = w1;
    }
    asm volatile("s_waitcnt lgkmcnt(0)" ::: "memory");

#pragma unroll
    for (int kh = 0; kh < 2; ++kh) {
      const bf16x8 pf0 = *(const bf16x8*)&P[col][kh * 32 + quad * 8];
      const bf16x8 pf1 = *(const bf16x8*)&P[16 + col][kh * 32 + quad * 8];
#pragma unroll
      for (int hh = 0; hh < 2; ++hh) {
        const int hd = hh * 16 + col;
        const bf16x8 vf = *(const bf16x8*)&vb[hd * AKT + (((kh * 4 + quad) ^ (hd & 7)) * 8)];
        o[0][hh] = __builtin_amdgcn_mfma_f32_16x16x32_bf16(pf0, vf, o[0][hh], 0, 0, 0);
        o[1][hh] = __builtin_amdgcn_mfma_f32_16x16x32_bf16(pf1, vf, o[1][hh], 0, 0, 0);
      }
      lacc0 = __builtin_amdgcn_mfma_f32_16x16x32_bf16(pf0, ones, lacc0, 0, 0, 0);
      lacc1 = __builtin_amdgcn_mfma_f32_16x16x32_bf16(pf1, ones, lacc1, 0, 0, 0);
    }
    cur ^= 1;
  }

  // diagonal self-key chunk: only hz==1 blocks with test queries (uniform)
  if (hz == 1 && blockIdx.x >= SPLITN / 128) {
#pragma unroll
    for (int qsub = 0; qsub < 2; ++qsub) {
      const int qd = q0 + qsub * 16;
      const bf16x8 qf = qsub ? qf1 : qf0;
      const bf16x8 kf = *(const bf16x8*)(kbase + (size_t)(qd + col) * 768 + quad * 8);
      const f32x4 sd = __builtin_amdgcn_mfma_f32_16x16x32_bf16(kf, qf, fz, 0, 0, 0);
      float pd[4];
#pragma unroll
      for (int r = 0; r < 4; ++r)
        pd[r] = (quad * 4 + r) == col ? fast_exp2(sd[r]) : 0.f;
      uint2 w0, wz; wz.x = 0; wz.y = 0;
      w0.x = pack2bf(pd[0], pd[1]); w0.y = pack2bf(pd[2], pd[3]);
      *(uint2*)&P[qsub * 16 + col][quad * 4] = w0;
      *(uint2*)&P[qsub * 16 + col][16 + quad * 4] = wz;
    }
    asm volatile("s_waitcnt lgkmcnt(0)" ::: "memory");
#pragma unroll
    for (int qsub = 0; qsub < 2; ++qsub) {
      const int qd = q0 + qsub * 16;
      const bf16x8 pf = *(const bf16x8*)&P[qsub * 16 + col][quad * 8];
#pragma unroll
      for (int hh = 0; hh < 2; ++hh) {
        const bf16x8 vf = *(const bf16x8*)(vtb + (size_t)(hh * 16 + col) * TSEQ + qd + quad * 8);
        o[qsub][hh] = __builtin_amdgcn_mfma_f32_16x16x32_bf16(pf, vf, o[qsub][hh], 0, 0, 0);
      }
      if (qsub == 0) lacc0 = __builtin_amdgcn_mfma_f32_16x16x32_bf16(pf, ones, lacc0, 0, 0, 0);
      else           lacc1 = __builtin_amdgcn_mfma_f32_16x16x32_bf16(pf, ones, lacc1, 0, 0, 0);
    }
  }

  // partial epilogue (un-normalized fp32 O + l)
  float* Ob = Opart + (size_t)hz * MROWS * DIM;
  float* lb = lpart + (size_t)hz * 16 * TSEQ + (size_t)bh * TSEQ;
#pragma unroll
  for (int qsub = 0; qsub < 2; ++qsub) {
    const f32x4 la = qsub ? lacc1 : lacc0;
    const int qq = q0 + qsub * 16 + quad * 4;
    const int rowb = b * TSEQ + qq;
#pragma unroll
    for (int r = 0; r < 4; ++r) {
      if (col == 0) lb[qq + r] = la[r];
#pragma unroll
      for (int hh = 0; hh < 2; ++hh)
        Ob[(size_t)(rowb + r) * DIM + h * HDIM + hh * 16 + col] = o[qsub][hh][r];
    }
  }
}

// ---------------------------------------------------------------- combine
__global__ __launch_bounds__(256) void attn_combine(
    const float* __restrict__ Opart, const float* __restrict__ lpart,
    short* __restrict__ ob)
{
  const int idx4 = blockIdx.x * 256 + threadIdx.x;  // float4 index
  const int row = idx4 >> 6, d4 = idx4 & 63;
  const int h = d4 >> 3, b = row >> 12, t = row & (TSEQ - 1);
  const int bh = b * 8 + h;
  const float l = lpart[bh * TSEQ + t] + lpart[16 * TSEQ + bh * TSEQ + t];
  const float4 o0 = ((const float4*)Opart)[idx4];
  const float4 o1 = ((const float4*)Opart)[(size_t)MROWS * (DIM / 4) + idx4];
  const float linv = 1.0f / l;
  short4 pk;
  pk.x = f2bf((o0.x + o1.x) * linv);
  pk.y = f2bf((o0.y + o1.y) * linv);
  pk.z = f2bf((o0.z + o1.z) * linv);
  pk.w = f2bf((o0.w + o1.w) * linv);
  ((short4*)ob)[idx4] = pk;
}

// ------------------------------------------------------------------ launch
extern "C" void kernel_launch(void* const* d_in, const int* in_sizes, int n_in,
                              void* d_out, int out_size, void* d_ws, size_t ws_size,
                              hipStream_t stream)
{
  const float* rows = (const float*)d_in[0];
  const float* tte  = (const float*)d_in[1];
  const float* Wq = (const float*)d_in[2];  const float* bq = (const float*)d_in[3];
  const float* Wk = (const float*)d_in[4];  const float* bk = (const float*)d_in[5];
  const float* Wv = (const float*)d_in[6];  const float* bv = (const float*)d_in[7];
  const float* Wo = (const float*)d_in[8];  const float* bo = (const float*)d_in[9];
  const float* W1 = (const float*)d_in[10]; const float* b1 = (const float*)d_in[11];
  const float* W2 = (const float*)d_in[12]; const float* b2 = (const float*)d_in[13];
  const float* ln1s = (const float*)d_in[14]; const float* ln1b = (const float*)d_in[15];
  const float* ln2s = (const float*)d_in[16]; const float* ln2b = (const float*)d_in[17];

  char* p = (char*)d_ws;
  float* xf   = (float*)p;  p += (size_t)MROWS * DIM * 4;
  short* xb   = (short*)p;  p += (size_t)MROWS * DIM * 2;
  short* qkv  = (short*)p;  p += (size_t)MROWS * 768 * 2;
  short* vtb  = (short*)p;  p += (size_t)BATCH * DIM * TSEQ * 2;
  short* ob   = (short*)p;  p += (size_t)MROWS * DIM * 2;
  short* hb   = (short*)p;  p += (size_t)MROWS * FFDIM * 2;
  float* Opart = (float*)p; p += (size_t)2 * MROWS * DIM * 4;
  float* lpart = (float*)p; p += (size_t)2 * 16 * TSEQ * 4;
  short* qkvT = (short*)p;  p += (size_t)NLAYER * 768 * DIM * 2;
  short* woT  = (short*)p;  p += (size_t)NLAYER * DIM * DIM * 2;
  short* w1T  = (short*)p;  p += (size_t)NLAYER * FFDIM * DIM * 2;
  short* w2T  = (short*)p;  p += (size_t)NLAYER * DIM * FFDIM * 2;

  prep_w<<<2048, 256, 0, stream>>>(Wq, Wk, Wv, Wo, W1, W2, qkvT, woT, w1T, w2T);
  prep_x<<<MROWS * DIM / 4 / 256, 256, 0, stream>>>(rows, tte, xf, xb);

  for (int l = 0; l < NLAYER; ++l) {
    gemm_bt<1><<<dim3(MROWS / GBM, 768 / GBN), 256, 0, stream>>>(
        xb, qkvT + (size_t)l * 768 * DIM, bq + l * DIM, bk + l * DIM, bv + l * DIM,
        qkv, MROWS, 768, DIM);
    transpose_v<<<dim3(TSEQ / 32, DIM / 32, BATCH), 256, 0, stream>>>(qkv, vtb);
    attn_kernel<<<dim3(TSEQ / 128, BATCH * NHEAD, 2), 256, 0, stream>>>(qkv, vtb, Opart, lpart);
    attn_combine<<<MROWS * DIM / 4 / 256, 256, 0, stream>>>(Opart, lpart, ob);
    gemm_ln<<<MROWS / 32, 256, 0, stream>>>(
        ob, woT + (size_t)l * DIM * DIM, bo + l * DIM, xf,
        ln1s + l * DIM, ln1b + l * DIM, xf, xb, DIM);
    gemm_bt<3><<<dim3(MROWS / GBM, FFDIM / GBN), 256, 0, stream>>>(
        xb, w1T + (size_t)l * FFDIM * DIM, b1 + l * FFDIM, nullptr, nullptr,
        hb, MROWS, FFDIM, DIM);
    float* xo = (l == NLAYER - 1) ? (float*)d_out : xf;
    gemm_ln<<<MROWS / 32, 256, 0, stream>>>(
        hb, w2T + (size_t)l * DIM * FFDIM, b2 + l * DIM, xf,
        ln2s + l * DIM, ln2b + l * DIM, xo, xb, FFDIM);
  }
}

// Round 8
// 512.412 us; speedup vs baseline: 1.6844x; 1.0346x over previous
//
#include <hip/hip_runtime.h>
#include <cstdint>
#include <cstddef>

#define TSEQ 4096
#define BATCH 2
#define DIM 256
#define NHEAD 8
#define HDIM 32
#define NLAYER 4
#define FFDIM 1024
#define SPLITN 2048
#define MROWS (BATCH * TSEQ)   // 8192

// (1/sqrt(HD)) * log2(e)  -- folded into q at the QKV epilogue so softmax uses exp2 directly
#define QSCALE 0.2550784545f

typedef __attribute__((ext_vector_type(4))) float f32x4;
typedef __attribute__((ext_vector_type(8))) short bf16x8;

__device__ __forceinline__ short f2bf(float f) {
  union { float f; uint32_t u; } v; v.f = f;
  uint32_t r = v.u + 0x7fffu + ((v.u >> 16) & 1u);
  return (short)(r >> 16);
}

__device__ __forceinline__ float bf2f(short s) {
  union { uint32_t u; float f; } v; v.u = ((uint32_t)(uint16_t)s) << 16;
  return v.f;
}

__device__ __forceinline__ float fast_exp2(float x) {
#if __has_builtin(__builtin_amdgcn_exp2f)
  return __builtin_amdgcn_exp2f(x);
#else
  float r;
  asm volatile("v_exp_f32 %0, %1\n\ts_nop 1" : "=v"(r) : "v"(x));
  return r;
#endif
}

// pack two fp32 -> two bf16 (round-half-up; 3 VALU ops)
__device__ __forceinline__ uint32_t pack2bf(float a, float b) {
  union { float f; uint32_t u; } ua, ub; ua.f = a; ub.f = b;
  return ((ua.u + 0x8000u) >> 16) | ((ub.u + 0x8000u) & 0xffff0000u);
}

__device__ __forceinline__ float gelu_f(float x) {
  float u = 0.7978845608f * x * (1.0f + 0.044715f * x * x);
  u = fminf(fmaxf(u, -20.f), 20.f);
  float e = fast_exp2(2.885390082f * u);   // exp(2u)
  float t = (e - 1.0f) / (e + 1.0f);
  return 0.5f * x * (1.0f + t);
}

#define AS1 __attribute__((address_space(1)))
#define AS3 __attribute__((address_space(3)))
__device__ __forceinline__ void gload16(const void* g, void* l) {
  __builtin_amdgcn_global_load_lds((AS1 void*)g, (AS3 void*)l, 16, 0, 0);
}

// ---------------------------------------------------------------- weight prep
__global__ __launch_bounds__(256) void prep_w(
    const float* __restrict__ Wq, const float* __restrict__ Wk,
    const float* __restrict__ Wv, const float* __restrict__ Wo,
    const float* __restrict__ W1, const float* __restrict__ W2,
    short* __restrict__ qkvT, short* __restrict__ woT,
    short* __restrict__ w1T, short* __restrict__ w2T)
{
  const int NQKV = NLAYER * 768 * DIM;
  const int NO   = NLAYER * DIM * DIM;
  const int NF   = NLAYER * FFDIM * DIM;
  const int total = NQKV + NO + 2 * NF;
  for (int idx = blockIdx.x * 256 + threadIdx.x; idx < total; idx += gridDim.x * 256) {
    if (idx < NQKV) {                       // qkvT[l][n:768][k:256]
      const int l = idx / (768 * DIM);
      const int rem = idx - l * 768 * DIM;
      const int n = rem >> 8, k = rem & 255;
      const float* src = (n < 256) ? Wq : ((n < 512) ? Wk : Wv);
      qkvT[idx] = f2bf(src[((size_t)l * DIM + k) * DIM + (n & 255)]);
    } else if (idx < NQKV + NO) {           // woT[l][n:256][k:256]
      const int j = idx - NQKV;
      const int l = j >> 16;
      const int rem = j & 65535;
      const int n = rem >> 8, k = rem & 255;
      woT[j] = f2bf(Wo[((size_t)l * DIM + k) * DIM + n]);
    } else if (idx < NQKV + NO + NF) {      // w1T[l][n:1024][k:256]
      const int j = idx - NQKV - NO;
      const int l = j >> 18;
      const int rem = j & 262143;
      const int n = rem >> 8, k = rem & 255;
      w1T[j] = f2bf(W1[((size_t)l * DIM + k) * FFDIM + n]);
    } else {                                // w2T[l][n:256][k:1024]
      const int j = idx - NQKV - NO - NF;
      const int l = j >> 18;
      const int rem = j & 262143;
      const int n = rem >> 10, k = rem & 1023;
      w2T[j] = f2bf(W2[((size_t)l * FFDIM + k) * DIM + n]);
    }
  }
}

// ------------------------------------------------------------------- x prep
__global__ __launch_bounds__(256) void prep_x(
    const float* __restrict__ rows, const float* __restrict__ tte,
    float* __restrict__ xf, short* __restrict__ xb)
{
  const size_t idx = (size_t)blockIdx.x * 256 + threadIdx.x;  // float4 index
  float4 v = ((const float4*)rows)[idx];
  const size_t e = idx * 4;
  const int m = (int)(e >> 8);
  const int d = (int)(e & 255);
  const int t = m & (TSEQ - 1);
  const int bb = m >> 12;
  if (t < SPLITN) {
    const float4 a = ((const float4*)tte)[((size_t)bb * SPLITN + t) * (DIM / 4) + (d >> 2)];
    v.x += a.x; v.y += a.y; v.z += a.z; v.w += a.w;
  }
  ((float4*)xf)[idx] = v;
  short4 pk; pk.x = f2bf(v.x); pk.y = f2bf(v.y); pk.z = f2bf(v.z); pk.w = f2bf(v.w);
  ((short4*)xb)[idx] = pk;
}

// ---------------------------------------------------------------------- GEMM
// (m97 pattern)  EPI: 1=qkv (+bias, q scaled, bf16)  3=gelu bf16
#define GBM 128
#define GBN 64
#define GBK 64

template<int EPI>
__global__ __launch_bounds__(256, 4) void gemm_bt(
    const short* __restrict__ A, const short* __restrict__ BT,
    const float* __restrict__ bias0, const float* __restrict__ bias1,
    const float* __restrict__ bias2, void* __restrict__ Cout,
    int M, int N, int K)
{
  __shared__ short As[GBM * GBK];
  __shared__ short Bs[GBN * GBK];
  const int tid = threadIdx.x;
  const int lane = tid & 63;
  const int wave = tid >> 6;
  const int wm = wave & 1, wn = wave >> 1;
  const int col = lane & 15, quad = lane >> 4;

  const short* Ab = A + (size_t)blockIdx.x * GBM * K;
  const short* Bb = BT + (size_t)blockIdx.y * GBN * K;

  const f32x4 fz = {0.f, 0.f, 0.f, 0.f};
  f32x4 acc[4][2];
#pragma unroll
  for (int i = 0; i < 4; ++i)
#pragma unroll
    for (int j = 0; j < 2; ++j) acc[i][j] = fz;

  for (int k0 = 0; k0 < K; k0 += GBK) {
#pragma unroll
    for (int p = 0; p < 4; ++p) {
      int i = p * 256 + tid;
      gload16(Ab + (size_t)(i >> 3) * K + k0 + (i & 7) * 8, &As[i * 8]);
    }
#pragma unroll
    for (int p = 0; p < 2; ++p) {
      int i = p * 256 + tid;
      gload16(Bb + (size_t)(i >> 3) * K + k0 + (i & 7) * 8, &Bs[i * 8]);
    }
    __syncthreads();
#pragma unroll
    for (int ks = 0; ks < GBK; ks += 32) {
      bf16x8 af[4], bfr[2];
#pragma unroll
      for (int tm = 0; tm < 4; ++tm)
        af[tm] = *(const bf16x8*)&As[(wm * 64 + tm * 16 + col) * GBK + ks + quad * 8];
#pragma unroll
      for (int tn = 0; tn < 2; ++tn)
        bfr[tn] = *(const bf16x8*)&Bs[(wn * 32 + tn * 16 + col) * GBK + ks + quad * 8];
#pragma unroll
      for (int tm = 0; tm < 4; ++tm)
#pragma unroll
        for (int tn = 0; tn < 2; ++tn)
          acc[tm][tn] = __builtin_amdgcn_mfma_f32_16x16x32_bf16(af[tm], bfr[tn], acc[tm][tn], 0, 0, 0);
    }
    __syncthreads();
  }

#pragma unroll
  for (int tm = 0; tm < 4; ++tm) {
    const int mbase = blockIdx.x * GBM + wm * 64 + tm * 16 + quad * 4;
#pragma unroll
    for (int tn = 0; tn < 2; ++tn) {
      const int n = blockIdx.y * GBN + wn * 32 + tn * 16 + col;
      float bv;
      if (EPI == 1) bv = (n < 256) ? bias0[n] : ((n < 512) ? bias1[n - 256] : bias2[n - 512]);
      else          bv = bias0[n];
#pragma unroll
      for (int r = 0; r < 4; ++r) {
        float v = acc[tm][tn][r] + bv;
        size_t off = (size_t)(mbase + r) * N + n;
        if (EPI == 1) {
          if (n < 256) v *= QSCALE;
          ((short*)Cout)[off] = f2bf(v);
        } else {
          ((short*)Cout)[off] = f2bf(gelu_f(v));
        }
      }
    }
  }
}

// ------------------------------------------------ GEMM + residual + LN fused
// C = A@BT^T + bias (N=256 full), out = LN(xres + C)*gs + gb.  M-tile 32,
// 4 waves (wave w -> cols w*64..+63, all 32 rows).
// MODE 0: A = bf16 matrix (regular load -> swizzled ds_write_b128).
// MODE 1: A = combined attention output, staged from Opart (2 key-halves,
//         fp32) + lpart on the fly (removes the combine kernel + ob buffer).
// As stored with XOR granule swizzle (g^row&7) -> conflict-free frag reads.
template<int MODE>
__global__ __launch_bounds__(256, 3) void gemm_ln(
    const short* __restrict__ A, const float* __restrict__ Opart,
    const float* __restrict__ lpart,
    const short* __restrict__ BT, const float* __restrict__ bias,
    const float* __restrict__ xres,
    const float* __restrict__ gs, const float* __restrict__ gb,
    float* __restrict__ xoutf, short* __restrict__ xoutb, int K)
{
  __shared__ short As[32 * 64];
  __shared__ short Bs[256 * 64];
  __shared__ float ssum[4][32], ssq[4][32];
  const int tid = threadIdx.x;
  const int lane = tid & 63;
  const int wave = tid >> 6;
  const int col = lane & 15, quad = lane >> 4;
  const int m0 = blockIdx.x * 32;

  const f32x4 fz = {0.f, 0.f, 0.f, 0.f};
  f32x4 acc[2][4];
#pragma unroll
  for (int i = 0; i < 2; ++i)
#pragma unroll
    for (int j = 0; j < 4; ++j) acc[i][j] = fz;

  // per-thread A-staging coords (one 16B granule per thread per K-tile)
  const int arow = tid >> 3;          // 0..31
  const int agr  = tid & 7;           // granule (8 cols)
  const int grow = m0 + arow;

  for (int k0 = 0; k0 < K; k0 += 64) {
    if (MODE == 0) {
      const bf16x8 av = *(const bf16x8*)(A + (size_t)grow * K + k0 + agr * 8);
      *(bf16x8*)&As[arow * 64 + ((agr ^ (arow & 7)) * 8)] = av;
    } else {
      const int tt = grow & (TSEQ - 1), bb = grow >> 12;
      const int head = (k0 >> 5) + (agr >= 4 ? 1 : 0);   // (k0 + agr*8)>>5
      const size_t lidx = (size_t)(bb * 8 + head) * TSEQ + tt;
      const float l = lpart[lidx] + lpart[(size_t)16 * TSEQ + lidx];
      const float li = 1.0f / l;
      const size_t obase = (size_t)grow * DIM + k0 + agr * 8;
      const float4 a0 = *(const float4*)(Opart + obase);
      const float4 a1 = *(const float4*)(Opart + obase + 4);
      const float4 c0 = *(const float4*)(Opart + (size_t)MROWS * DIM + obase);
      const float4 c1 = *(const float4*)(Opart + (size_t)MROWS * DIM + obase + 4);
      uint4 w;
      w.x = pack2bf((a0.x + c0.x) * li, (a0.y + c0.y) * li);
      w.y = pack2bf((a0.z + c0.z) * li, (a0.w + c0.w) * li);
      w.z = pack2bf((a1.x + c1.x) * li, (a1.y + c1.y) * li);
      w.w = pack2bf((a1.z + c1.z) * li, (a1.w + c1.w) * li);
      *(uint4*)&As[arow * 64 + ((agr ^ (arow & 7)) * 8)] = w;
    }
#pragma unroll
    for (int p = 0; p < 8; ++p) {
      int i = p * 256 + tid;
      gload16(BT + (size_t)(i >> 3) * K + k0 + (i & 7) * 8, &Bs[i * 8]);
    }
    __syncthreads();
#pragma unroll
    for (int ks = 0; ks < 64; ks += 32) {
      bf16x8 af[2], bfr[4];
#pragma unroll
      for (int tm = 0; tm < 2; ++tm) {
        const int row = tm * 16 + col;
        const int g = (ks >> 3) + quad;
        af[tm] = *(const bf16x8*)&As[row * 64 + ((g ^ (row & 7)) * 8)];
      }
#pragma unroll
      for (int tn = 0; tn < 4; ++tn)
        bfr[tn] = *(const bf16x8*)&Bs[(wave * 64 + tn * 16 + col) * 64 + ks + quad * 8];
#pragma unroll
      for (int tm = 0; tm < 2; ++tm)
#pragma unroll
        for (int tn = 0; tn < 4; ++tn)
          acc[tm][tn] = __builtin_amdgcn_mfma_f32_16x16x32_bf16(af[tm], bfr[tn], acc[tm][tn], 0, 0, 0);
    }
    __syncthreads();
  }

  // v = acc + bias + residual
  const float* resb = xres + (size_t)m0 * DIM;
#pragma unroll
  for (int tn = 0; tn < 4; ++tn) {
    const int n = wave * 64 + tn * 16 + col;
    const float bv = bias[n];
#pragma unroll
    for (int tm = 0; tm < 2; ++tm)
#pragma unroll
      for (int r = 0; r < 4; ++r) {
        const int row = tm * 16 + quad * 4 + r;
        acc[tm][tn][r] += bv + resb[(size_t)row * DIM + n];
      }
  }

  // per-row LN stats
#pragma unroll
  for (int tm = 0; tm < 2; ++tm)
#pragma unroll
    for (int r = 0; r < 4; ++r) {
      float s = 0.f, q = 0.f;
#pragma unroll
      for (int tn = 0; tn < 4; ++tn) { const float v = acc[tm][tn][r]; s += v; q += v * v; }
      s += __shfl_xor(s, 1); q += __shfl_xor(q, 1);
      s += __shfl_xor(s, 2); q += __shfl_xor(q, 2);
      s += __shfl_xor(s, 4); q += __shfl_xor(q, 4);
      s += __shfl_xor(s, 8); q += __shfl_xor(q, 8);
      if (col == 0) { const int row = tm * 16 + quad * 4 + r; ssum[wave][row] = s; ssq[wave][row] = q; }
    }
  __syncthreads();
  if (tid < 32) {
    const float S = ssum[0][tid] + ssum[1][tid] + ssum[2][tid] + ssum[3][tid];
    const float Q = ssq[0][tid] + ssq[1][tid] + ssq[2][tid] + ssq[3][tid];
    const float mu = S * (1.0f / DIM);
    const float var = Q * (1.0f / DIM) - mu * mu;
    ssum[0][tid] = mu;
    ssq[0][tid] = rsqrtf(var + 1e-5f);
  }
  __syncthreads();

#pragma unroll
  for (int tm = 0; tm < 2; ++tm)
#pragma unroll
    for (int tn = 0; tn < 4; ++tn) {
      const int n = wave * 64 + tn * 16 + col;
      const float g = gs[n], bb = gb[n];
#pragma unroll
      for (int r = 0; r < 4; ++r) {
        const int row = tm * 16 + quad * 4 + r;
        const float out = (acc[tm][tn][r] - ssum[0][row]) * ssq[0][row] * g + bb;
        xoutf[(size_t)(m0 + row) * DIM + n] = out;
        xoutb[(size_t)(m0 + row) * DIM + n] = f2bf(out);
      }
    }
}

// ----------------------------------------------------------------- attention
// Key-split x2 (blockIdx.z).  Block = 128 queries of one (b,h); 4 waves x 32q.
// K staged via global_load_lds in hd-part planes [part][key] (conflict-free).
// V staged straight from qkv: per thread one 16B load (8 hd of one key) +
// 8 ds_write_b16 into swizzled [hd][key] plane; V-loads pipelined one full
// tile ahead.  Diagonal self-key handled elementwise (no V^T needed).
#define AKT 64
#define KSPL 1024
#define NKT (KSPL / AKT)

__global__ __launch_bounds__(256, 4) void attn_kernel(
    const short* __restrict__ qkv,
    float* __restrict__ Opart, float* __restrict__ lpart)
{
  __shared__ short Kbuf[2][AKT * HDIM];   // [part(4)][key(64)][8]
  __shared__ short Vbuf[2][HDIM * AKT];   // [hd][key-swz]
  __shared__ short Pall[4][32][72];       // per-wave P, padded rows
  __shared__ float Pdiag[4][16];

  const int tid = threadIdx.x;
  const int lane = tid & 63;
  const int wave = tid >> 6;
  const int col = lane & 15, quad = lane >> 4;
  const int bh = blockIdx.y;
  const int b = bh >> 3, h = bh & 7;
  const int hz = blockIdx.z;
  const int q0 = blockIdx.x * 128 + wave * 32;

  short (*P)[72] = Pall[wave];

  const short* qbase = qkv + (size_t)b * TSEQ * 768 + h * HDIM;
  const short* kbase = qbase + 256;
  const short* vcol  = qbase + 512;

  // K staging: thread -> key tid&63, part tid>>6 (gload16, lane-linear dest)
  const short* ksrc = kbase + (size_t)(hz * KSPL + (tid & 63)) * 768 + (tid >> 6) * 8;
  // V staging: thread -> key tid&63, hd-group tid>>6 (8 hd, 16B contiguous)
  const int vkey = tid & 63, vhg = tid >> 6;
  const int va = vkey >> 3, vb8 = vkey & 7;
  const short* vsrc = vcol + (size_t)(hz * KSPL + vkey) * 768 + vhg * 8;

  const bf16x8 qf0 = *(const bf16x8*)(qbase + (size_t)(q0 + col) * 768 + quad * 8);
  const bf16x8 qf1 = *(const bf16x8*)(qbase + (size_t)(q0 + 16 + col) * 768 + quad * 8);

  bf16x8 ones;
#pragma unroll
  for (int i = 0; i < 8; ++i) ones[i] = (short)0x3F80;

  const f32x4 fz = {0.f, 0.f, 0.f, 0.f};
  f32x4 o[2][2] = {{fz, fz}, {fz, fz}};
  f32x4 lacc[2] = {fz, fz};

  // prologue: stage tile 0 (K via DMA, V via load+ds_write), prefetch V tile 1
  gload16(ksrc, &Kbuf[0][tid * 8]);
  {
    const bf16x8 v0 = *(const bf16x8*)vsrc;
#pragma unroll
    for (int j = 0; j < 8; ++j)
      Vbuf[0][(vhg * 8 + j) * 64 + ((va ^ j) * 8) + vb8] = v0[j];
  }
  bf16x8 vnext = *(const bf16x8*)(vsrc + (size_t)AKT * 768);

  int cur = 0;
  for (int t = 0; t < NKT; ++t) {
    __syncthreads();
    if (t + 1 < NKT) {
      gload16(ksrc + (size_t)(t + 1) * AKT * 768, &Kbuf[1 - cur][tid * 8]);
#pragma unroll
      for (int j = 0; j < 8; ++j)
        Vbuf[1 - cur][(vhg * 8 + j) * 64 + ((va ^ j) * 8) + vb8] = vnext[j];
      if (t + 2 < NKT) vnext = *(const bf16x8*)(vsrc + (size_t)(t + 2) * AKT * 768);
    }
    const short* kb = Kbuf[cur];
    const short* vb = Vbuf[cur];

    // ---- S phase
#pragma unroll
    for (int st = 0; st < 4; ++st) {
      const bf16x8 kf = *(const bf16x8*)&kb[(quad * 64 + st * 16 + col) * 8];
      const f32x4 s0 = __builtin_amdgcn_mfma_f32_16x16x32_bf16(kf, qf0, fz, 0, 0, 0);
      const f32x4 s1 = __builtin_amdgcn_mfma_f32_16x16x32_bf16(kf, qf1, fz, 0, 0, 0);
      uint2 w0, w1;
      w0.x = pack2bf(fast_exp2(s0[0]), fast_exp2(s0[1]));
      w0.y = pack2bf(fast_exp2(s0[2]), fast_exp2(s0[3]));
      w1.x = pack2bf(fast_exp2(s1[0]), fast_exp2(s1[1]));
      w1.y = pack2bf(fast_exp2(s1[2]), fast_exp2(s1[3]));
      *(uint2*)&P[col][st * 16 + quad * 4] = w0;
      *(uint2*)&P[16 + col][st * 16 + quad * 4] = w1;
    }
    asm volatile("s_waitcnt lgkmcnt(0)" ::: "memory");

    // ---- PV phase
#pragma unroll
    for (int kh = 0; kh < 2; ++kh) {
      const bf16x8 pf0 = *(const bf16x8*)&P[col][kh * 32 + quad * 8];
      const bf16x8 pf1 = *(const bf16x8*)&P[16 + col][kh * 32 + quad * 8];
#pragma unroll
      for (int hh = 0; hh < 2; ++hh) {
        const int hd = hh * 16 + col;
        const bf16x8 vf = *(const bf16x8*)&vb[hd * AKT + (((kh * 4 + quad) ^ (hd & 7)) * 8)];
        o[0][hh] = __builtin_amdgcn_mfma_f32_16x16x32_bf16(pf0, vf, o[0][hh], 0, 0, 0);
        o[1][hh] = __builtin_amdgcn_mfma_f32_16x16x32_bf16(pf1, vf, o[1][hh], 0, 0, 0);
      }
      lacc[0] = __builtin_amdgcn_mfma_f32_16x16x32_bf16(pf0, ones, lacc[0], 0, 0, 0);
      lacc[1] = __builtin_amdgcn_mfma_f32_16x16x32_bf16(pf1, ones, lacc[1], 0, 0, 0);
    }
    cur ^= 1;
  }

  // ---- diagonal self-key (elementwise: p_self * V[q]) for test-query blocks
  if (hz == 1 && blockIdx.x >= SPLITN / 128) {
#pragma unroll
    for (int qsub = 0; qsub < 2; ++qsub) {
      const int qd = q0 + qsub * 16;
      const bf16x8 qf = qsub ? qf1 : qf0;
      const bf16x8 kf = *(const bf16x8*)(kbase + (size_t)(qd + col) * 768 + quad * 8);
      const f32x4 sd = __builtin_amdgcn_mfma_f32_16x16x32_bf16(kf, qf, fz, 0, 0, 0);
      // diagonal element for query=col lives at lane quad==col>>2, r==col&3
      float ps = 0.f;
#pragma unroll
      for (int r = 0; r < 4; ++r)
        if (quad * 4 + r == col) ps = fast_exp2(sd[r]);
      if (quad == (col >> 2)) Pdiag[wave][col] = ps;
      asm volatile("s_waitcnt lgkmcnt(0)" ::: "memory");
      const f32x4 pv = *(const f32x4*)&Pdiag[wave][quad * 4];  // broadcast
#pragma unroll
      for (int r = 0; r < 4; ++r) {
        lacc[qsub][r] += pv[r];
        const size_t vrow = (size_t)(qd + quad * 4 + r) * 768;
#pragma unroll
        for (int hh = 0; hh < 2; ++hh)
          o[qsub][hh][r] += pv[r] * bf2f(vcol[vrow + hh * 16 + col]);
      }
      asm volatile("s_waitcnt lgkmcnt(0)" ::: "memory");  // before qsub1 rewrite
    }
  }

  // ---- partial epilogue (un-normalized fp32 O + l)
  float* Ob = Opart + (size_t)hz * MROWS * DIM;
  float* lb = lpart + (size_t)hz * 16 * TSEQ + (size_t)bh * TSEQ;
#pragma unroll
  for (int qsub = 0; qsub < 2; ++qsub) {
    const f32x4 la = lacc[qsub];
    const int qq = q0 + qsub * 16 + quad * 4;
    const int rowb = b * TSEQ + qq;
#pragma unroll
    for (int r = 0; r < 4; ++r) {
      if (col == 0) lb[qq + r] = la[r];
#pragma unroll
      for (int hh = 0; hh < 2; ++hh)
        Ob[(size_t)(rowb + r) * DIM + h * HDIM + hh * 16 + col] = o[qsub][hh][r];
    }
  }
}

// ------------------------------------------------------------------ launch
extern "C" void kernel_launch(void* const* d_in, const int* in_sizes, int n_in,
                              void* d_out, int out_size, void* d_ws, size_t ws_size,
                              hipStream_t stream)
{
  const float* rows = (const float*)d_in[0];
  const float* tte  = (const float*)d_in[1];
  const float* Wq = (const float*)d_in[2];  const float* bq = (const float*)d_in[3];
  const float* Wk = (const float*)d_in[4];  const float* bk = (const float*)d_in[5];
  const float* Wv = (const float*)d_in[6];  const float* bv = (const float*)d_in[7];
  const float* Wo = (const float*)d_in[8];  const float* bo = (const float*)d_in[9];
  const float* W1 = (const float*)d_in[10]; const float* b1 = (const float*)d_in[11];
  const float* W2 = (const float*)d_in[12]; const float* b2 = (const float*)d_in[13];
  const float* ln1s = (const float*)d_in[14]; const float* ln1b = (const float*)d_in[15];
  const float* ln2s = (const float*)d_in[16]; const float* ln2b = (const float*)d_in[17];

  char* p = (char*)d_ws;
  float* xf   = (float*)p;  p += (size_t)MROWS * DIM * 4;
  short* xb   = (short*)p;  p += (size_t)MROWS * DIM * 2;
  short* qkv  = (short*)p;  p += (size_t)MROWS * 768 * 2;
  short* hb   = (short*)p;  p += (size_t)MROWS * FFDIM * 2;
  float* Opart = (float*)p; p += (size_t)2 * MROWS * DIM * 4;
  float* lpart = (float*)p; p += (size_t)2 * 16 * TSEQ * 4;
  short* qkvT = (short*)p;  p += (size_t)NLAYER * 768 * DIM * 2;
  short* woT  = (short*)p;  p += (size_t)NLAYER * DIM * DIM * 2;
  short* w1T  = (short*)p;  p += (size_t)NLAYER * FFDIM * DIM * 2;
  short* w2T  = (short*)p;  p += (size_t)NLAYER * DIM * FFDIM * 2;

  prep_w<<<2048, 256, 0, stream>>>(Wq, Wk, Wv, Wo, W1, W2, qkvT, woT, w1T, w2T);
  prep_x<<<MROWS * DIM / 4 / 256, 256, 0, stream>>>(rows, tte, xf, xb);

  for (int l = 0; l < NLAYER; ++l) {
    gemm_bt<1><<<dim3(MROWS / GBM, 768 / GBN), 256, 0, stream>>>(
        xb, qkvT + (size_t)l * 768 * DIM, bq + l * DIM, bk + l * DIM, bv + l * DIM,
        qkv, MROWS, 768, DIM);
    attn_kernel<<<dim3(TSEQ / 128, BATCH * NHEAD, 2), 256, 0, stream>>>(qkv, Opart, lpart);
    gemm_ln<1><<<MROWS / 32, 256, 0, stream>>>(
        nullptr, Opart, lpart, woT + (size_t)l * DIM * DIM, bo + l * DIM, xf,
        ln1s + l * DIM, ln1b + l * DIM, xf, xb, DIM);
    gemm_bt<3><<<dim3(MROWS / GBM, FFDIM / GBN), 256, 0, stream>>>(
        xb, w1T + (size_t)l * FFDIM * DIM, b1 + l * FFDIM, nullptr, nullptr,
        hb, MROWS, FFDIM, DIM);
    float* xo = (l == NLAYER - 1) ? (float*)d_out : xf;
    gemm_ln<0><<<MROWS / 32, 256, 0, stream>>>(
        hb, nullptr, nullptr, w2T + (size_t)l * DIM * FFDIM,
        b2 + l * DIM, xf, ln2s + l * DIM, ln2b + l * DIM, xo, xb, FFDIM);
  }
}